// Round 6
// baseline (332.449 us; speedup 1.0000x reference)
//
#include <hip/hip_runtime.h>
#include <math.h>

// SEM_40200893890649 R6: ONE kernel, software grid barriers (128 blocks x 256).
// Phases: P0 scorer | P1 chunk scores+top64 | P2 merge+policy+ne0T | P3 A-gather+GRU | P4 GCN

namespace {
constexpr int B_ = 32;
constexpr int N_ = 2000;
constexpr int D_ = 128;
constexpr int R_ = 640;
constexpr int NB = 128;  // grid size

constexpr size_t OFF_SCORER = 0;        // [32][128]
constexpr size_t OFF_INVN   = 4096;     // [32]
constexpr size_t OFF_CANDV  = 4128;     // [32][4][64]
constexpr size_t OFF_CANDI  = 12320;    // int
constexpr size_t OFF_STATS  = 20512;    // [32][4][3]
constexpr size_t OFF_TKI    = 20896;    // int [32][64]
constexpr size_t OFF_T0     = 22944;    // [32][64]
constexpr size_t OFF_NE0T   = 24992;    // [32][128][64]
constexpr size_t OFF_A0R    = 287136;   // [32][64][64]
constexpr size_t OFF_DW     = 418208;   // [32][128][128]
constexpr size_t OFF_H1     = 942496;   // [32][64][128]
}  // namespace

__device__ int g_barA[8];
__device__ int g_barB[8];

namespace {

__device__ __forceinline__ void gridbar(int slot) {
  __syncthreads();
  if (threadIdx.x == 0) {
    __threadfence();
    atomicAdd(&g_barA[slot], 1);
    while (__hip_atomic_load(&g_barA[slot], __ATOMIC_ACQUIRE,
                             __HIP_MEMORY_SCOPE_AGENT) < NB)
      __builtin_amdgcn_s_sleep(2);
    const int prev = atomicAdd(&g_barB[slot], 1);
    if (prev == NB - 1) {  // last through: restore zeros for next launch
      __hip_atomic_store(&g_barA[slot], 0, __ATOMIC_RELAXED, __HIP_MEMORY_SCOPE_AGENT);
      __hip_atomic_store(&g_barB[slot], 0, __ATOMIC_RELEASE, __HIP_MEMORY_SCOPE_AGENT);
    }
    __threadfence();
  }
  __syncthreads();
}

struct Params {
  const float *Ahat, *node, *ht, *prevD, *mw, *mb;
  const float *Wu, *Uu, *bu, *Wr, *Ur, *br, *Wh, *Uh, *bh, *sw;
  float *out, *outPolicy, *outScorer, *outEntropy;
  float *scorer, *invn, *cand_v;
  int *cand_i;
  float *stats;
  int *tki;
  float *t0v, *ne0T, *A0r, *Dw, *h1;
};

union Smem {
  struct { float sh[R_]; float part[2][128]; float red[2]; } p0;
  struct { float sc[D_]; float cv[256]; int ci[256]; float r1[4], r2[4]; } p1;
  struct { float cv[256]; int ci[256]; float sv[64]; int si[64];
           float lne[64][132]; } p2;
  struct { float Wt[16][132], Ut[16][132]; float Xt[16][36], Yt[16][36];
           float gs[2][128][33]; float t0s[32]; } p3;
  struct { float As[64][68]; float di[64];
           union { struct { float At[16][68]; float Bt[16][68]; } st;
                   float Ts[64][68]; } u; } p4;
};

__global__ __launch_bounds__(256) void mono(Params p) {
  __shared__ Smem S;
  const int blk = blockIdx.x, t = threadIdx.x;

  // ---------------- P0: scorer (blocks 0..31) ----------------
  if (blk < 32) {
    const int b = blk, d = t & 127, half = t >> 7;
    for (int j = t; j < R_; j += 256) S.p0.sh[j] = p.ht[b * R_ + j];
    __syncthreads();
    const float* w = p.mw + (size_t)d * R_ + half * 320;
    const float* hh = S.p0.sh + half * 320;
    float acc = 0.f;
    for (int j = 0; j < 320; j += 4) {
      float4 wv = *reinterpret_cast<const float4*>(w + j);
      acc += wv.x * hh[j] + wv.y * hh[j + 1] + wv.z * hh[j + 2] + wv.w * hh[j + 3];
    }
    S.p0.part[half][d] = acc;
    __syncthreads();
    if (t < 128) {
      float s = tanhf(S.p0.part[0][t] + S.p0.part[1][t] + p.mb[t]);
      p.scorer[b * D_ + t] = s;
      p.outScorer[b * D_ + t] = s;
      float ss = s * s;
      #pragma unroll
      for (int o = 32; o > 0; o >>= 1) ss += __shfl_down(ss, o);
      if ((t & 63) == 0) S.p0.red[t >> 6] = ss;
    }
    __syncthreads();
    if (t == 0) p.invn[b] = 1.0f / sqrtf(S.p0.red[0] + S.p0.red[1]);
  }
  gridbar(0);

  // ------- P1: chunk scores (500 rows) + stats + wave-local top64 + block merge -------
  {
    const int b = blk >> 2, c = blk & 3;
    const int lane = t & 63, w = t >> 6;
    if (t < D_) S.p1.sc[t] = p.scorer[b * D_ + t];
    __syncthreads();
    const float inv = p.invn[b];
    const int base = c * 500;
    const int n0 = base + t;
    const int n1 = base + 256 + t;
    float v0, v1 = -INFINITY;
    {
      const float* row = p.node + ((size_t)b * N_ + n0) * D_;
      float acc = 0.f;
      for (int j = 0; j < D_; j += 4) {
        float4 a = *reinterpret_cast<const float4*>(row + j);
        acc += a.x * S.p1.sc[j] + a.y * S.p1.sc[j + 1] +
               a.z * S.p1.sc[j + 2] + a.w * S.p1.sc[j + 3];
      }
      v0 = acc * inv;
    }
    if (t < 244) {
      const float* row = p.node + ((size_t)b * N_ + n1) * D_;
      float acc = 0.f;
      for (int j = 0; j < D_; j += 4) {
        float4 a = *reinterpret_cast<const float4*>(row + j);
        acc += a.x * S.p1.sc[j] + a.y * S.p1.sc[j + 1] +
               a.z * S.p1.sc[j + 2] + a.w * S.p1.sc[j + 3];
      }
      v1 = acc * inv;
    }
    float m = fmaxf(v0, v1);
    #pragma unroll
    for (int o = 32; o > 0; o >>= 1) m = fmaxf(m, __shfl_xor(m, o));
    if (lane == 0) S.p1.r1[w] = m;
    __syncthreads();
    const float Mc = fmaxf(fmaxf(S.p1.r1[0], S.p1.r1[1]), fmaxf(S.p1.r1[2], S.p1.r1[3]));
    __syncthreads();
    float se, sx;
    {
      const float x0 = v0 - Mc;
      const float e0 = expf(x0);
      se = e0;
      sx = x0 * e0;
      if (t < 244) {
        const float x1 = v1 - Mc;
        const float e1 = expf(x1);
        se += e1;
        sx += x1 * e1;
      }
    }
    #pragma unroll
    for (int o = 32; o > 0; o >>= 1) {
      se += __shfl_xor(se, o);
      sx += __shfl_xor(sx, o);
    }
    if (lane == 0) { S.p1.r1[w] = se; S.p1.r2[w] = sx; }
    __syncthreads();
    if (t == 0) {
      float* st = p.stats + ((size_t)b * 4 + c) * 3;
      st[0] = Mc;
      st[1] = S.p1.r1[0] + S.p1.r1[1] + S.p1.r1[2] + S.p1.r1[3];
      st[2] = S.p1.r2[0] + S.p1.r2[1] + S.p1.r2[2] + S.p1.r2[3];
    }
    // wave-local top-64 extraction (lockstep, no barriers)
    float x0 = v0, x1 = v1;
    for (int k = 0; k < 64; ++k) {
      float bv;
      int bi;
      if (x1 > x0) { bv = x1; bi = n1; } else { bv = x0; bi = n0; }
      #pragma unroll
      for (int o = 1; o < 64; o <<= 1) {
        const float ov = __shfl_xor(bv, o);
        const int oi = __shfl_xor(bi, o);
        if (ov > bv || (ov == bv && oi < bi)) { bv = ov; bi = oi; }
      }
      if (lane == 0) { S.p1.cv[w * 64 + k] = bv; S.p1.ci[w * 64 + k] = bi; }
      if (bi == n0) x0 = -INFINITY;
      else if (bi == n1) x1 = -INFINITY;
    }
    __syncthreads();
    // block rank-merge of 256 candidates -> chunk top-64
    const float mv = S.p1.cv[t];
    const int mi = S.p1.ci[t];
    int rank = 0;
    for (int j = 0; j < 256; ++j) {
      const float jv = S.p1.cv[j];
      const int ji = S.p1.ci[j];
      rank += (jv > mv || (jv == mv && ji < mi)) ? 1 : 0;
    }
    if (rank < 64) {
      p.cand_v[((size_t)b * 4 + c) * 64 + rank] = mv;
      p.cand_i[((size_t)b * 4 + c) * 64 + rank] = mi;
    }
  }
  gridbar(1);

  // ------- P2 (blocks 0..31): merge 256 -> top64, policy/entropy, ne0T gather -------
  if (blk < 32) {
    const int b = blk;
    S.p2.cv[t] = p.cand_v[(size_t)b * 256 + t];
    S.p2.ci[t] = p.cand_i[(size_t)b * 256 + t];
    __syncthreads();
    {
      const float mv = S.p2.cv[t];
      const int mi = S.p2.ci[t];
      int rank = 0;
      for (int j = 0; j < 256; ++j) {
        const float jv = S.p2.cv[j];
        const int ji = S.p2.ci[j];
        rank += (jv > mv || (jv == mv && ji < mi)) ? 1 : 0;
      }
      if (rank < 64) { S.p2.sv[rank] = mv; S.p2.si[rank] = mi; }
    }
    __syncthreads();
    if (t < 64) {
      p.tki[b * 64 + t] = S.p2.si[t];
      const float v = S.p2.sv[t];
      p.t0v[b * 64 + t] = tanhf(v);
      float s = v;
      #pragma unroll
      for (int o = 32; o > 0; o >>= 1) s += __shfl_xor(s, o);
      if (t == 0) {
        float M = -INFINITY;
        for (int c = 0; c < 4; ++c) M = fmaxf(M, p.stats[((size_t)b * 4 + c) * 3]);
        float se = 0.f, sx = 0.f;
        for (int c = 0; c < 4; ++c) {
          const float* st = p.stats + ((size_t)b * 4 + c) * 3;
          const float f = expf(st[0] - M);
          se += f * st[1];
          sx += f * (st[2] + (st[0] - M) * st[1]);
        }
        const float logS = logf(se);
        p.outPolicy[b] = s * (1.0f / 64.0f) - M - logS;
        p.outEntropy[b] = logS - sx / se;
      }
    }
    __syncthreads();
    {
      const int k = t >> 2, q = t & 3;
      const float* src = p.node + ((size_t)b * N_ + S.p2.si[k]) * D_ + q * 32;
      #pragma unroll
      for (int j = 0; j < 32; j += 4)
        *reinterpret_cast<float4*>(&S.p2.lne[k][q * 32 + j]) =
            *reinterpret_cast<const float4*>(src + j);
    }
    __syncthreads();
    {
      const int f = t >> 1, kh = (t & 1) * 32;
      float* dst = p.ne0T + ((size_t)b * D_ + f) * 64 + kh;
      #pragma unroll
      for (int j = 0; j < 32; j += 4) {
        float4 v;
        v.x = S.p2.lne[kh + j][f];
        v.y = S.p2.lne[kh + j + 1][f];
        v.z = S.p2.lne[kh + j + 2][f];
        v.w = S.p2.lne[kh + j + 3][f];
        *reinterpret_cast<float4*>(dst + j) = v;
      }
    }
  }
  gridbar(2);

  // ---------------- P3: A-gather (all blocks) then GRU (all blocks) ----------------
  {
    const int b = blk >> 2, y = blk & 3;
    const int j = t & 63, li = t >> 6;
    const int cj = p.tki[b * 64 + j];
    const float* Ab = p.Ahat + (size_t)b * N_ * N_;
    float* dst = p.A0r + (size_t)b * 4096;
    #pragma unroll
    for (int s = 0; s < 4; ++s) {
      const int i = y * 16 + s * 4 + li;
      dst[i * 64 + j] = Ab[(size_t)p.tki[b * 64 + i] * N_ + cj];
    }
  }
  {
    const int b = blk >> 2, c = blk & 3;
    const int tx = t & 15, ty = t >> 4;
    if (t < 32) S.p3.t0s[t] = p.t0v[b * 64 + (c & 1) * 32 + t];
    const float* neT = p.ne0T + (size_t)b * D_ * 64;
    const float* Pb = p.prevD + (size_t)b * D_ * D_;
    for (int z = 0; z < 2; ++z) {
      const float* W = z ? p.Wr : p.Wu;
      const float* U = z ? p.Ur : p.Uu;
      const float* bb = z ? p.br : p.bu;
      float acc[8][2] = {};
      for (int f0 = 0; f0 < D_; f0 += 16) {
        __syncthreads();
        #pragma unroll
        for (int rr = 0; rr < 8; rr++) {
          const int i = rr * 16 + ty;
          S.p3.Wt[tx][i] = W[i * D_ + f0 + tx];
          S.p3.Ut[tx][i] = U[i * D_ + f0 + tx];
        }
        {
          const int ff = ty, kk = tx * 2;
          S.p3.Xt[ff][kk]     = neT[(f0 + ff) * 64 + (c & 1) * 32 + kk] * S.p3.t0s[kk];
          S.p3.Xt[ff][kk + 1] = neT[(f0 + ff) * 64 + (c & 1) * 32 + kk + 1] * S.p3.t0s[kk + 1];
          const float2 p2 = *reinterpret_cast<const float2*>(Pb + (f0 + ff) * D_ + c * 32 + kk);
          S.p3.Yt[ff][kk] = p2.x;
          S.p3.Yt[ff][kk + 1] = p2.y;
        }
        __syncthreads();
        #pragma unroll
        for (int ff = 0; ff < 16; ff++) {
          const float xv0 = S.p3.Xt[ff][tx * 2], xv1 = S.p3.Xt[ff][tx * 2 + 1];
          const float yv0 = S.p3.Yt[ff][tx * 2], yv1 = S.p3.Yt[ff][tx * 2 + 1];
          const float4 wa = *reinterpret_cast<const float4*>(&S.p3.Wt[ff][ty * 8]);
          const float4 wb = *reinterpret_cast<const float4*>(&S.p3.Wt[ff][ty * 8 + 4]);
          const float4 ua = *reinterpret_cast<const float4*>(&S.p3.Ut[ff][ty * 8]);
          const float4 ub = *reinterpret_cast<const float4*>(&S.p3.Ut[ff][ty * 8 + 4]);
          const float wv[8] = {wa.x, wa.y, wa.z, wa.w, wb.x, wb.y, wb.z, wb.w};
          const float uv[8] = {ua.x, ua.y, ua.z, ua.w, ub.x, ub.y, ub.z, ub.w};
          #pragma unroll
          for (int r = 0; r < 8; r++) {
            acc[r][0] += wv[r] * xv0 + uv[r] * yv0;
            acc[r][1] += wv[r] * xv1 + uv[r] * yv1;
          }
        }
      }
      #pragma unroll
      for (int r = 0; r < 8; r++) {
        const int i = ty * 8 + r;
        #pragma unroll
        for (int cc = 0; cc < 2; cc++) {
          const int kk = tx * 2 + cc;
          const float zz = acc[r][cc] + bb[i * D_ + c * 32 + kk];
          S.p3.gs[z][i][kk] = 1.f / (1.f + expf(-zz));
        }
      }
    }
    float acc[8][2] = {};
    for (int f0 = 0; f0 < D_; f0 += 16) {
      __syncthreads();
      #pragma unroll
      for (int rr = 0; rr < 8; rr++) {
        const int i = rr * 16 + ty;
        S.p3.Wt[tx][i] = p.Wh[i * D_ + f0 + tx];
        S.p3.Ut[tx][i] = p.Uh[i * D_ + f0 + tx];
      }
      {
        const int ff = ty, kk = tx * 2;
        S.p3.Xt[ff][kk]     = neT[(f0 + ff) * 64 + (c & 1) * 32 + kk] * S.p3.t0s[kk];
        S.p3.Xt[ff][kk + 1] = neT[(f0 + ff) * 64 + (c & 1) * 32 + kk + 1] * S.p3.t0s[kk + 1];
        const float2 p2 = *reinterpret_cast<const float2*>(Pb + (f0 + ff) * D_ + c * 32 + kk);
        S.p3.Yt[ff][kk]     = S.p3.gs[1][f0 + ff][kk] * p2.x;
        S.p3.Yt[ff][kk + 1] = S.p3.gs[1][f0 + ff][kk + 1] * p2.y;
      }
      __syncthreads();
      #pragma unroll
      for (int ff = 0; ff < 16; ff++) {
        const float xv0 = S.p3.Xt[ff][tx * 2], xv1 = S.p3.Xt[ff][tx * 2 + 1];
        const float yv0 = S.p3.Yt[ff][tx * 2], yv1 = S.p3.Yt[ff][tx * 2 + 1];
        const float4 wa = *reinterpret_cast<const float4*>(&S.p3.Wt[ff][ty * 8]);
        const float4 wb = *reinterpret_cast<const float4*>(&S.p3.Wt[ff][ty * 8 + 4]);
        const float4 ua = *reinterpret_cast<const float4*>(&S.p3.Ut[ff][ty * 8]);
        const float4 ub = *reinterpret_cast<const float4*>(&S.p3.Ut[ff][ty * 8 + 4]);
        const float wv[8] = {wa.x, wa.y, wa.z, wa.w, wb.x, wb.y, wb.z, wb.w};
        const float uv[8] = {ua.x, ua.y, ua.z, ua.w, ub.x, ub.y, ub.z, ub.w};
        #pragma unroll
        for (int r = 0; r < 8; r++) {
          acc[r][0] += wv[r] * xv0 + uv[r] * yv0;
          acc[r][1] += wv[r] * xv1 + uv[r] * yv1;
        }
      }
    }
    #pragma unroll
    for (int r = 0; r < 8; r++) {
      const int i = ty * 8 + r;
      #pragma unroll
      for (int cc = 0; cc < 2; cc++) {
        const int kk = tx * 2 + cc;
        const int k = c * 32 + kk;
        const size_t off = ((size_t)b * D_ + i) * D_ + k;
        const float hh = tanhf(acc[r][cc] + p.bh[i * D_ + k]);
        const float uu = S.p3.gs[0][i][kk];
        const float pp = Pb[i * D_ + k];
        p.Dw[off] = (1.f - uu) * pp + uu * hh;
      }
    }
  }
  gridbar(3);

  // ---------------- P4 (blocks 0..31): whole GCN per batch ----------------
  if (blk < 32) {
    const int b = blk;
    const int tx = t & 15, ty = t >> 4;
    const float* Ab = p.A0r + (size_t)b * 4096;
    const float* neT = p.ne0T + (size_t)b * D_ * 64;
    const float* Db = p.Dw + (size_t)b * D_ * D_;
    float* h1b = p.h1 + (size_t)b * 64 * D_;
    #pragma unroll
    for (int ph = 0; ph < 4; ++ph) {
      const int i = ph * 16 + ty;
      *reinterpret_cast<float4*>(&S.p4.As[i][tx * 4]) =
          *reinterpret_cast<const float4*>(Ab + i * 64 + tx * 4);
    }
    __syncthreads();
    if (t < 64) {
      float s = 0.f;
      #pragma unroll
      for (int i = 0; i < 64; ++i) s += S.p4.As[i][t];
      S.p4.di[t] = 1.0f / sqrtf(2.0f * s);
    }
    __syncthreads();
    #pragma unroll
    for (int ph = 0; ph < 4; ++ph) {
      const int i = ph * 16 + ty;
      const float sI = 2.0f * S.p4.di[i];
      float4 v = *reinterpret_cast<float4*>(&S.p4.As[i][tx * 4]);
      v.x *= sI * S.p4.di[tx * 4];
      v.y *= sI * S.p4.di[tx * 4 + 1];
      v.z *= sI * S.p4.di[tx * 4 + 2];
      v.w *= sI * S.p4.di[tx * 4 + 3];
      *reinterpret_cast<float4*>(&S.p4.As[i][tx * 4]) = v;
    }
    for (int c = 0; c < 2; ++c) {
      float acc[4][4] = {};
      for (int f0 = 0; f0 < D_; f0 += 16) {
        __syncthreads();
        {
          const int ff = t >> 4, i4 = (t & 15) * 4;
          *reinterpret_cast<float4*>(&S.p4.u.st.At[ff][i4]) =
              *reinterpret_cast<const float4*>(neT + (f0 + ff) * 64 + i4);
          *reinterpret_cast<float4*>(&S.p4.u.st.Bt[ff][i4]) =
              *reinterpret_cast<const float4*>(Db + (f0 + ff) * D_ + c * 64 + i4);
        }
        __syncthreads();
        #pragma unroll
        for (int ff = 0; ff < 16; ff++) {
          const float4 av = *reinterpret_cast<const float4*>(&S.p4.u.st.At[ff][ty * 4]);
          const float4 bv = *reinterpret_cast<const float4*>(&S.p4.u.st.Bt[ff][tx * 4]);
          const float a_[4] = {av.x, av.y, av.z, av.w};
          const float b_[4] = {bv.x, bv.y, bv.z, bv.w};
          #pragma unroll
          for (int r = 0; r < 4; r++)
            #pragma unroll
            for (int cc = 0; cc < 4; cc++) acc[r][cc] += a_[r] * b_[cc];
        }
      }
      __syncthreads();
      #pragma unroll
      for (int r = 0; r < 4; r++) {
        float4 o = {acc[r][0], acc[r][1], acc[r][2], acc[r][3]};
        *reinterpret_cast<float4*>(&S.p4.u.Ts[ty * 4 + r][tx * 4]) = o;
      }
      __syncthreads();
      float acc2[4][4] = {};
      for (int ff = 0; ff < 64; ++ff) {
        const float4 bv = *reinterpret_cast<const float4*>(&S.p4.u.Ts[ff][tx * 4]);
        const float b_[4] = {bv.x, bv.y, bv.z, bv.w};
        #pragma unroll
        for (int r = 0; r < 4; r++) {
          const float a = S.p4.As[ty * 4 + r][ff];
          #pragma unroll
          for (int cc = 0; cc < 4; cc++) acc2[r][cc] += a * b_[cc];
        }
      }
      #pragma unroll
      for (int r = 0; r < 4; r++) {
        float4 o = {fmaxf(acc2[r][0], 0.f), fmaxf(acc2[r][1], 0.f),
                    fmaxf(acc2[r][2], 0.f), fmaxf(acc2[r][3], 0.f)};
        *reinterpret_cast<float4*>(h1b + (ty * 4 + r) * D_ + c * 64 + tx * 4) = o;
      }
    }
    __syncthreads();
    for (int c = 0; c < 2; ++c) {
      float acc[4][4] = {};
      for (int f0 = 0; f0 < D_; f0 += 16) {
        __syncthreads();
        {
          const int ff = t >> 4, i4 = (t & 15) * 4;
          #pragma unroll
          for (int s = 0; s < 4; ++s)
            S.p4.u.st.At[ff][i4 + s] = h1b[(i4 + s) * D_ + f0 + ff];
          *reinterpret_cast<float4*>(&S.p4.u.st.Bt[ff][i4]) =
              *reinterpret_cast<const float4*>(p.sw + (f0 + ff) * D_ + c * 64 + i4);
        }
        __syncthreads();
        #pragma unroll
        for (int ff = 0; ff < 16; ff++) {
          const float4 av = *reinterpret_cast<const float4*>(&S.p4.u.st.At[ff][ty * 4]);
          const float4 bv = *reinterpret_cast<const float4*>(&S.p4.u.st.Bt[ff][tx * 4]);
          const float a_[4] = {av.x, av.y, av.z, av.w};
          const float b_[4] = {bv.x, bv.y, bv.z, bv.w};
          #pragma unroll
          for (int r = 0; r < 4; r++)
            #pragma unroll
            for (int cc = 0; cc < 4; cc++) acc[r][cc] += a_[r] * b_[cc];
        }
      }
      __syncthreads();
      #pragma unroll
      for (int r = 0; r < 4; r++) {
        float4 o = {acc[r][0], acc[r][1], acc[r][2], acc[r][3]};
        *reinterpret_cast<float4*>(&S.p4.u.Ts[ty * 4 + r][tx * 4]) = o;
      }
      __syncthreads();
      float acc2[4][4] = {};
      for (int ff = 0; ff < 64; ++ff) {
        const float4 bv = *reinterpret_cast<const float4*>(&S.p4.u.Ts[ff][tx * 4]);
        const float b_[4] = {bv.x, bv.y, bv.z, bv.w};
        #pragma unroll
        for (int r = 0; r < 4; r++) {
          const float a = S.p4.As[ty * 4 + r][ff];
          #pragma unroll
          for (int cc = 0; cc < 4; cc++) acc2[r][cc] += a * b_[cc];
        }
      }
      #pragma unroll
      for (int r = 0; r < 4; r++) {
        const int i = ty * 4 + r;
        const int k = c * 64 + tx * 4;
        const float4 h1v = *reinterpret_cast<const float4*>(h1b + i * D_ + k);
        float4 o;
        o.x = 0.5f * (h1v.x + fmaxf(acc2[r][0], 0.f));
        o.y = 0.5f * (h1v.y + fmaxf(acc2[r][1], 0.f));
        o.z = 0.5f * (h1v.z + fmaxf(acc2[r][2], 0.f));
        o.w = 0.5f * (h1v.w + fmaxf(acc2[r][3], 0.f));
        *reinterpret_cast<float4*>(p.out + ((size_t)b * D_ + i) * D_ + k) = o;
        *reinterpret_cast<float4*>(p.out + ((size_t)b * D_ + i + 64) * D_ + k) = o;
      }
    }
  }
}

}  // namespace

extern "C" void kernel_launch(void* const* d_in, const int* in_sizes, int n_in,
                              void* d_out, int out_size, void* d_ws, size_t ws_size,
                              hipStream_t stream) {
  (void)in_sizes; (void)n_in; (void)out_size; (void)ws_size;
  float* out = (float*)d_out;
  float* ws = (float*)d_ws;

  Params p;
  p.Ahat = (const float*)d_in[0];
  p.node = (const float*)d_in[1];
  p.ht   = (const float*)d_in[2];
  p.prevD= (const float*)d_in[3];
  p.mw   = (const float*)d_in[4];
  p.mb   = (const float*)d_in[5];
  p.Wu   = (const float*)d_in[6];
  p.Uu   = (const float*)d_in[7];
  p.bu   = (const float*)d_in[8];
  p.Wr   = (const float*)d_in[9];
  p.Ur   = (const float*)d_in[10];
  p.br   = (const float*)d_in[11];
  p.Wh   = (const float*)d_in[12];
  p.Uh   = (const float*)d_in[13];
  p.bh   = (const float*)d_in[14];
  p.sw   = (const float*)d_in[15];
  p.out        = out;
  p.outPolicy  = out + (size_t)B_ * D_ * D_;
  p.outScorer  = p.outPolicy + B_;
  p.outEntropy = p.outScorer + (size_t)B_ * D_;
  p.scorer = ws + OFF_SCORER;
  p.invn   = ws + OFF_INVN;
  p.cand_v = ws + OFF_CANDV;
  p.cand_i = (int*)(ws + OFF_CANDI);
  p.stats  = ws + OFF_STATS;
  p.tki    = (int*)(ws + OFF_TKI);
  p.t0v    = ws + OFF_T0;
  p.ne0T   = ws + OFF_NE0T;
  p.A0r    = ws + OFF_A0R;
  p.Dw     = ws + OFF_DW;
  p.h1     = ws + OFF_H1;

  mono<<<NB, 256, 0, stream>>>(p);
}

// Round 7
// 304.431 us; speedup vs baseline: 1.0920x; 1.0920x over previous
//
#include <hip/hip_runtime.h>
#include <math.h>

// SEM_40200893890649 R7: minimal 3-kernel pipeline.
//  K1 (grid 32): scorer + 2000 scores + softmax stats + top-64 + policy/entropy
//                + ne0T gather/transpose + scattered A-gather
//  K2 (grid 32x4): fused GRU (R5 body)
//  K3 (grid 32): whole GCN per batch (R5 body)

namespace {
constexpr int B_ = 32;
constexpr int N_ = 2000;
constexpr int D_ = 128;
constexpr int R_ = 640;

// ---------- workspace layout (float offsets) ----------
constexpr size_t OFF_T0   = 0;        // [32][64]
constexpr size_t OFF_NE0T = 2048;     // [32][128][64]
constexpr size_t OFF_A0R  = 264192;   // [32][64][64] raw gathered
constexpr size_t OFF_DW   = 395264;   // [32][128][128]
constexpr size_t OFF_H1   = 919552;   // [32][64][128]
// end 1181696 floats = 4.5 MiB

// =============== K1: everything up to the GRU inputs, one block per batch ===============
__global__ __launch_bounds__(256) void k1_all(
    const float* __restrict__ node, const float* __restrict__ ht,
    const float* __restrict__ mw, const float* __restrict__ mb,
    const float* __restrict__ Ahat,
    float* __restrict__ outScorer, float* __restrict__ outPolicy,
    float* __restrict__ outEntropy, float* __restrict__ t0v,
    float* __restrict__ ne0T, float* __restrict__ A0r) {
  const int b = blockIdx.x, t = threadIdx.x;
  const int lane = t & 63, w = t >> 6;
  __shared__ float sh[R_];
  __shared__ float part[2][128];
  __shared__ float sc[D_];
  __shared__ float red1[4], red2[4];
  __shared__ float cv[256];
  __shared__ int ci[256];
  __shared__ float sv[64];
  __shared__ int si[64];
  __shared__ float lne[64][132];

  // ---- scorer = tanh(ht @ mw^T + mb); 1/||scorer|| ----
  for (int j = t; j < R_; j += 256) sh[j] = ht[b * R_ + j];
  __syncthreads();
  {
    const int d = t & 127, half = t >> 7;
    const float* wp = mw + (size_t)d * R_ + half * 320;
    const float* hh = sh + half * 320;
    float acc = 0.f;
    for (int j = 0; j < 320; j += 4) {
      float4 wv = *reinterpret_cast<const float4*>(wp + j);
      acc += wv.x * hh[j] + wv.y * hh[j + 1] + wv.z * hh[j + 2] + wv.w * hh[j + 3];
    }
    part[half][d] = acc;
  }
  __syncthreads();
  if (t < 128) {
    const float s = tanhf(part[0][t] + part[1][t] + mb[t]);
    sc[t] = s;
    outScorer[b * D_ + t] = s;
    float ss = s * s;
    #pragma unroll
    for (int o = 32; o > 0; o >>= 1) ss += __shfl_down(ss, o);
    if ((t & 63) == 0) red1[t >> 6] = ss;
  }
  __syncthreads();
  const float inv = 1.0f / sqrtf(red1[0] + red1[1]);
  __syncthreads();  // red1 reused below

  // ---- scores: 8 rows per thread (rows t, t+256, ..., t+1792) ----
  float v[8];
  #pragma unroll
  for (int s = 0; s < 8; s++) {
    const int n = t + 256 * s;
    if (n < N_) {
      const float* row = node + ((size_t)b * N_ + n) * D_;
      float acc = 0.f;
      for (int j = 0; j < D_; j += 4) {
        float4 a = *reinterpret_cast<const float4*>(row + j);
        acc += a.x * sc[j] + a.y * sc[j + 1] + a.z * sc[j + 2] + a.w * sc[j + 3];
      }
      v[s] = acc * inv;
    } else {
      v[s] = -INFINITY;
    }
  }
  // ---- global max ----
  float m = v[0];
  #pragma unroll
  for (int s = 1; s < 8; s++) m = fmaxf(m, v[s]);
  #pragma unroll
  for (int o = 32; o > 0; o >>= 1) m = fmaxf(m, __shfl_xor(m, o));
  if (lane == 0) red1[w] = m;
  __syncthreads();
  const float M = fmaxf(fmaxf(red1[0], red1[1]), fmaxf(red1[2], red1[3]));
  __syncthreads();
  // ---- softmax sums ----
  float se = 0.f, sx = 0.f;
  #pragma unroll
  for (int s = 0; s < 8; s++) {
    if (t + 256 * s < N_) {
      const float x = v[s] - M;
      const float e = expf(x);
      se += e;
      sx += x * e;
    }
  }
  #pragma unroll
  for (int o = 32; o > 0; o >>= 1) {
    se += __shfl_xor(se, o);
    sx += __shfl_xor(sx, o);
  }
  if (lane == 0) { red1[w] = se; red2[w] = sx; }
  __syncthreads();
  const float Se = red1[0] + red1[1] + red1[2] + red1[3];
  const float Sx = red2[0] + red2[1] + red2[2] + red2[3];

  // ---- per-wave lockstep top-64 over this wave's 512 rows ----
  float x[8];
  #pragma unroll
  for (int s = 0; s < 8; s++) x[s] = v[s];
  for (int k = 0; k < 64; ++k) {
    float bv = x[0];
    int bi = t;
    #pragma unroll
    for (int s = 1; s < 8; s++) {
      const int n = t + 256 * s;
      if (x[s] > bv) { bv = x[s]; bi = n; }
    }
    #pragma unroll
    for (int o = 1; o < 64; o <<= 1) {
      const float ov = __shfl_xor(bv, o);
      const int oi = __shfl_xor(bi, o);
      if (ov > bv || (ov == bv && oi < bi)) { bv = ov; bi = oi; }
    }
    if (lane == 0) { cv[w * 64 + k] = bv; ci[w * 64 + k] = bi; }
    #pragma unroll
    for (int s = 0; s < 8; s++)
      if (bi == t + 256 * s) x[s] = -INFINITY;
  }
  __syncthreads();
  // ---- block rank-merge 256 -> exact sorted top-64 ----
  {
    const float mv = cv[t];
    const int mi = ci[t];
    int rank = 0;
    for (int j = 0; j < 256; ++j) {
      const float jv = cv[j];
      const int ji = ci[j];
      rank += (jv > mv || (jv == mv && ji < mi)) ? 1 : 0;
    }
    if (rank < 64) { sv[rank] = mv; si[rank] = mi; }
  }
  __syncthreads();
  // ---- t0v, policy, entropy ----
  if (t < 64) {
    const float val = sv[t];
    t0v[b * 64 + t] = tanhf(val);
    float s = val;
    #pragma unroll
    for (int o = 32; o > 0; o >>= 1) s += __shfl_xor(s, o);
    if (t == 0) {
      const float logS = logf(Se);
      outPolicy[b] = s * (1.0f / 64.0f) - M - logS;
      outEntropy[b] = logS - Sx / Se;
    }
  }
  __syncthreads();
  // ---- ne0T gather + transpose (via LDS) ----
  {
    const int k = t >> 2, q = t & 3;
    const float* src = node + ((size_t)b * N_ + si[k]) * D_ + q * 32;
    #pragma unroll
    for (int j = 0; j < 32; j += 4)
      *reinterpret_cast<float4*>(&lne[k][q * 32 + j]) =
          *reinterpret_cast<const float4*>(src + j);
  }
  __syncthreads();
  {
    const int f = t >> 1, kh = (t & 1) * 32;
    float* dst = ne0T + ((size_t)b * D_ + f) * 64 + kh;
    #pragma unroll
    for (int j = 0; j < 32; j += 4) {
      float4 vv;
      vv.x = lne[kh + j][f];
      vv.y = lne[kh + j + 1][f];
      vv.z = lne[kh + j + 2][f];
      vv.w = lne[kh + j + 3][f];
      *reinterpret_cast<float4*>(dst + j) = vv;
    }
  }
  // ---- scattered A-gather (raw; normalized later in K3) ----
  {
    const int j = t & 63, li = t >> 6;
    const int cj = si[j];
    const float* Ab = Ahat + (size_t)b * N_ * N_;
    float* dst = A0r + (size_t)b * 4096;
    #pragma unroll
    for (int s = 0; s < 16; ++s) {
      const int i = s * 4 + li;
      dst[i * 64 + j] = Ab[(size_t)si[i] * N_ + cj];
    }
  }
}

// =============== K2: fused GRU (proven R2/R4/R5) ===============
__global__ __launch_bounds__(256) void k2_gru(
    const float* __restrict__ Wu, const float* __restrict__ Uu, const float* __restrict__ bu,
    const float* __restrict__ Wr, const float* __restrict__ Ur, const float* __restrict__ br,
    const float* __restrict__ Wh, const float* __restrict__ Uh, const float* __restrict__ bh,
    const float* __restrict__ ne0T, const float* __restrict__ t0v,
    const float* __restrict__ P, float* __restrict__ Dw) {
  const int b = blockIdx.x, c = blockIdx.y;
  const int t = threadIdx.x, tx = t & 15, ty = t >> 4;
  __shared__ float Wt[16][132], Ut[16][132];
  __shared__ float Xt[16][36], Yt[16][36];
  __shared__ float gs[2][128][33];
  __shared__ float t0s[32];
  if (t < 32) t0s[t] = t0v[b * 64 + (c & 1) * 32 + t];
  const float* neT = ne0T + (size_t)b * D_ * 64;
  const float* Pb = P + (size_t)b * D_ * D_;
  for (int z = 0; z < 2; ++z) {
    const float* W = z ? Wr : Wu;
    const float* U = z ? Ur : Uu;
    const float* bb = z ? br : bu;
    float acc[8][2] = {};
    for (int f0 = 0; f0 < D_; f0 += 16) {
      __syncthreads();
      #pragma unroll
      for (int rr = 0; rr < 8; rr++) {
        const int i = rr * 16 + ty;
        Wt[tx][i] = W[i * D_ + f0 + tx];
        Ut[tx][i] = U[i * D_ + f0 + tx];
      }
      {
        const int ff = ty, kk = tx * 2;
        Xt[ff][kk]     = neT[(f0 + ff) * 64 + (c & 1) * 32 + kk] * t0s[kk];
        Xt[ff][kk + 1] = neT[(f0 + ff) * 64 + (c & 1) * 32 + kk + 1] * t0s[kk + 1];
        const float2 p2 = *reinterpret_cast<const float2*>(Pb + (f0 + ff) * D_ + c * 32 + kk);
        Yt[ff][kk] = p2.x;
        Yt[ff][kk + 1] = p2.y;
      }
      __syncthreads();
      #pragma unroll
      for (int ff = 0; ff < 16; ff++) {
        const float xv0 = Xt[ff][tx * 2], xv1 = Xt[ff][tx * 2 + 1];
        const float yv0 = Yt[ff][tx * 2], yv1 = Yt[ff][tx * 2 + 1];
        const float4 wa = *reinterpret_cast<const float4*>(&Wt[ff][ty * 8]);
        const float4 wb = *reinterpret_cast<const float4*>(&Wt[ff][ty * 8 + 4]);
        const float4 ua = *reinterpret_cast<const float4*>(&Ut[ff][ty * 8]);
        const float4 ub = *reinterpret_cast<const float4*>(&Ut[ff][ty * 8 + 4]);
        const float wv[8] = {wa.x, wa.y, wa.z, wa.w, wb.x, wb.y, wb.z, wb.w};
        const float uv[8] = {ua.x, ua.y, ua.z, ua.w, ub.x, ub.y, ub.z, ub.w};
        #pragma unroll
        for (int r = 0; r < 8; r++) {
          acc[r][0] += wv[r] * xv0 + uv[r] * yv0;
          acc[r][1] += wv[r] * xv1 + uv[r] * yv1;
        }
      }
    }
    #pragma unroll
    for (int r = 0; r < 8; r++) {
      const int i = ty * 8 + r;
      #pragma unroll
      for (int cc = 0; cc < 2; cc++) {
        const int kk = tx * 2 + cc;
        const float zz = acc[r][cc] + bb[i * D_ + c * 32 + kk];
        gs[z][i][kk] = 1.f / (1.f + expf(-zz));
      }
    }
  }
  float acc[8][2] = {};
  for (int f0 = 0; f0 < D_; f0 += 16) {
    __syncthreads();
    #pragma unroll
    for (int rr = 0; rr < 8; rr++) {
      const int i = rr * 16 + ty;
      Wt[tx][i] = Wh[i * D_ + f0 + tx];
      Ut[tx][i] = Uh[i * D_ + f0 + tx];
    }
    {
      const int ff = ty, kk = tx * 2;
      Xt[ff][kk]     = neT[(f0 + ff) * 64 + (c & 1) * 32 + kk] * t0s[kk];
      Xt[ff][kk + 1] = neT[(f0 + ff) * 64 + (c & 1) * 32 + kk + 1] * t0s[kk + 1];
      const float2 p2 = *reinterpret_cast<const float2*>(Pb + (f0 + ff) * D_ + c * 32 + kk);
      Yt[ff][kk]     = gs[1][f0 + ff][kk] * p2.x;
      Yt[ff][kk + 1] = gs[1][f0 + ff][kk + 1] * p2.y;
    }
    __syncthreads();
    #pragma unroll
    for (int ff = 0; ff < 16; ff++) {
      const float xv0 = Xt[ff][tx * 2], xv1 = Xt[ff][tx * 2 + 1];
      const float yv0 = Yt[ff][tx * 2], yv1 = Yt[ff][tx * 2 + 1];
      const float4 wa = *reinterpret_cast<const float4*>(&Wt[ff][ty * 8]);
      const float4 wb = *reinterpret_cast<const float4*>(&Wt[ff][ty * 8 + 4]);
      const float4 ua = *reinterpret_cast<const float4*>(&Ut[ff][ty * 8]);
      const float4 ub = *reinterpret_cast<const float4*>(&Ut[ff][ty * 8 + 4]);
      const float wv[8] = {wa.x, wa.y, wa.z, wa.w, wb.x, wb.y, wb.z, wb.w};
      const float uv[8] = {ua.x, ua.y, ua.z, ua.w, ub.x, ub.y, ub.z, ub.w};
      #pragma unroll
      for (int r = 0; r < 8; r++) {
        acc[r][0] += wv[r] * xv0 + uv[r] * yv0;
        acc[r][1] += wv[r] * xv1 + uv[r] * yv1;
      }
    }
  }
  #pragma unroll
  for (int r = 0; r < 8; r++) {
    const int i = ty * 8 + r;
    #pragma unroll
    for (int cc = 0; cc < 2; cc++) {
      const int kk = tx * 2 + cc;
      const int k = c * 32 + kk;
      const size_t off = ((size_t)b * D_ + i) * D_ + k;
      const float hh = tanhf(acc[r][cc] + bh[i * D_ + k]);
      const float uu = gs[0][i][kk];
      const float pp = Pb[i * D_ + k];
      Dw[off] = (1.f - uu) * pp + uu * hh;
    }
  }
}

// =============== K3: whole GCN per batch (proven R5) ===============
__global__ __launch_bounds__(256) void k3_gcn(
    const float* __restrict__ ne0T, const float* __restrict__ Dw,
    const float* __restrict__ A0r, const float* __restrict__ sw,
    float* __restrict__ h1ws, float* __restrict__ out) {
  const int b = blockIdx.x, t = threadIdx.x;
  const int tx = t & 15, ty = t >> 4;
  __shared__ float As[64][68];
  __shared__ float di[64];
  __shared__ union {
    struct { float At[16][68]; float Bt[16][68]; } st;
    float Ts[64][68];
  } Un;
  const float* Ab = A0r + (size_t)b * 4096;
  const float* neT = ne0T + (size_t)b * D_ * 64;
  const float* Db = Dw + (size_t)b * D_ * D_;
  float* h1b = h1ws + (size_t)b * 64 * D_;
  #pragma unroll
  for (int ph = 0; ph < 4; ++ph) {
    const int i = ph * 16 + ty;
    *reinterpret_cast<float4*>(&As[i][tx * 4]) =
        *reinterpret_cast<const float4*>(Ab + i * 64 + tx * 4);
  }
  __syncthreads();
  if (t < 64) {
    float s = 0.f;
    #pragma unroll
    for (int i = 0; i < 64; ++i) s += As[i][t];
    di[t] = 1.0f / sqrtf(2.0f * s);
  }
  __syncthreads();
  #pragma unroll
  for (int ph = 0; ph < 4; ++ph) {
    const int i = ph * 16 + ty;
    const float sI = 2.0f * di[i];
    float4 v = *reinterpret_cast<float4*>(&As[i][tx * 4]);
    v.x *= sI * di[tx * 4];
    v.y *= sI * di[tx * 4 + 1];
    v.z *= sI * di[tx * 4 + 2];
    v.w *= sI * di[tx * 4 + 3];
    *reinterpret_cast<float4*>(&As[i][tx * 4]) = v;
  }
  for (int c = 0; c < 2; ++c) {
    float acc[4][4] = {};
    for (int f0 = 0; f0 < D_; f0 += 16) {
      __syncthreads();
      {
        const int ff = t >> 4, i4 = (t & 15) * 4;
        *reinterpret_cast<float4*>(&Un.st.At[ff][i4]) =
            *reinterpret_cast<const float4*>(neT + (f0 + ff) * 64 + i4);
        *reinterpret_cast<float4*>(&Un.st.Bt[ff][i4]) =
            *reinterpret_cast<const float4*>(Db + (f0 + ff) * D_ + c * 64 + i4);
      }
      __syncthreads();
      #pragma unroll
      for (int ff = 0; ff < 16; ff++) {
        const float4 av = *reinterpret_cast<const float4*>(&Un.st.At[ff][ty * 4]);
        const float4 bv = *reinterpret_cast<const float4*>(&Un.st.Bt[ff][tx * 4]);
        const float a_[4] = {av.x, av.y, av.z, av.w};
        const float b_[4] = {bv.x, bv.y, bv.z, bv.w};
        #pragma unroll
        for (int r = 0; r < 4; r++)
          #pragma unroll
          for (int cc = 0; cc < 4; cc++) acc[r][cc] += a_[r] * b_[cc];
      }
    }
    __syncthreads();
    #pragma unroll
    for (int r = 0; r < 4; r++) {
      float4 o = {acc[r][0], acc[r][1], acc[r][2], acc[r][3]};
      *reinterpret_cast<float4*>(&Un.Ts[ty * 4 + r][tx * 4]) = o;
    }
    __syncthreads();
    float acc2[4][4] = {};
    for (int ff = 0; ff < 64; ++ff) {
      const float4 bv = *reinterpret_cast<const float4*>(&Un.Ts[ff][tx * 4]);
      const float b_[4] = {bv.x, bv.y, bv.z, bv.w};
      #pragma unroll
      for (int r = 0; r < 4; r++) {
        const float a = As[ty * 4 + r][ff];
        #pragma unroll
        for (int cc = 0; cc < 4; cc++) acc2[r][cc] += a * b_[cc];
      }
    }
    #pragma unroll
    for (int r = 0; r < 4; r++) {
      float4 o = {fmaxf(acc2[r][0], 0.f), fmaxf(acc2[r][1], 0.f),
                  fmaxf(acc2[r][2], 0.f), fmaxf(acc2[r][3], 0.f)};
      *reinterpret_cast<float4*>(h1b + (ty * 4 + r) * D_ + c * 64 + tx * 4) = o;
    }
  }
  __syncthreads();
  for (int c = 0; c < 2; ++c) {
    float acc[4][4] = {};
    for (int f0 = 0; f0 < D_; f0 += 16) {
      __syncthreads();
      {
        const int ff = t >> 4, i4 = (t & 15) * 4;
        #pragma unroll
        for (int s = 0; s < 4; ++s)
          Un.st.At[ff][i4 + s] = h1b[(i4 + s) * D_ + f0 + ff];
        *reinterpret_cast<float4*>(&Un.st.Bt[ff][i4]) =
            *reinterpret_cast<const float4*>(sw + (f0 + ff) * D_ + c * 64 + i4);
      }
      __syncthreads();
      #pragma unroll
      for (int ff = 0; ff < 16; ff++) {
        const float4 av = *reinterpret_cast<const float4*>(&Un.st.At[ff][ty * 4]);
        const float4 bv = *reinterpret_cast<const float4*>(&Un.st.Bt[ff][tx * 4]);
        const float a_[4] = {av.x, av.y, av.z, av.w};
        const float b_[4] = {bv.x, bv.y, bv.z, bv.w};
        #pragma unroll
        for (int r = 0; r < 4; r++)
          #pragma unroll
          for (int cc = 0; cc < 4; cc++) acc[r][cc] += a_[r] * b_[cc];
      }
    }
    __syncthreads();
    #pragma unroll
    for (int r = 0; r < 4; r++) {
      float4 o = {acc[r][0], acc[r][1], acc[r][2], acc[r][3]};
      *reinterpret_cast<float4*>(&Un.Ts[ty * 4 + r][tx * 4]) = o;
    }
    __syncthreads();
    float acc2[4][4] = {};
    for (int ff = 0; ff < 64; ++ff) {
      const float4 bv = *reinterpret_cast<const float4*>(&Un.Ts[ff][tx * 4]);
      const float b_[4] = {bv.x, bv.y, bv.z, bv.w};
      #pragma unroll
      for (int r = 0; r < 4; r++) {
        const float a = As[ty * 4 + r][ff];
        #pragma unroll
        for (int cc = 0; cc < 4; cc++) acc2[r][cc] += a * b_[cc];
      }
    }
    #pragma unroll
    for (int r = 0; r < 4; r++) {
      const int i = ty * 4 + r;
      const int k = c * 64 + tx * 4;
      const float4 h1v = *reinterpret_cast<const float4*>(h1b + i * D_ + k);
      float4 o;
      o.x = 0.5f * (h1v.x + fmaxf(acc2[r][0], 0.f));
      o.y = 0.5f * (h1v.y + fmaxf(acc2[r][1], 0.f));
      o.z = 0.5f * (h1v.z + fmaxf(acc2[r][2], 0.f));
      o.w = 0.5f * (h1v.w + fmaxf(acc2[r][3], 0.f));
      *reinterpret_cast<float4*>(out + ((size_t)b * D_ + i) * D_ + k) = o;
      *reinterpret_cast<float4*>(out + ((size_t)b * D_ + i + 64) * D_ + k) = o;
    }
  }
}

}  // namespace

extern "C" void kernel_launch(void* const* d_in, const int* in_sizes, int n_in,
                              void* d_out, int out_size, void* d_ws, size_t ws_size,
                              hipStream_t stream) {
  (void)in_sizes; (void)n_in; (void)out_size; (void)ws_size;
  const float* Ahat = (const float*)d_in[0];
  const float* node = (const float*)d_in[1];
  const float* ht   = (const float*)d_in[2];
  const float* prevD= (const float*)d_in[3];
  const float* mw   = (const float*)d_in[4];
  const float* mb   = (const float*)d_in[5];
  const float* Wu   = (const float*)d_in[6];
  const float* Uu   = (const float*)d_in[7];
  const float* bu   = (const float*)d_in[8];
  const float* Wr   = (const float*)d_in[9];
  const float* Ur   = (const float*)d_in[10];
  const float* br   = (const float*)d_in[11];
  const float* Wh   = (const float*)d_in[12];
  const float* Uh   = (const float*)d_in[13];
  const float* bh   = (const float*)d_in[14];
  const float* sw   = (const float*)d_in[15];

  float* out = (float*)d_out;
  float* outPolicy  = out + (size_t)B_ * D_ * D_;
  float* outScorer  = outPolicy + B_;
  float* outEntropy = outScorer + (size_t)B_ * D_;

  float* ws = (float*)d_ws;
  float* t0v  = ws + OFF_T0;
  float* ne0T = ws + OFF_NE0T;
  float* A0r  = ws + OFF_A0R;
  float* Dw   = ws + OFF_DW;
  float* h1ws = ws + OFF_H1;

  k1_all<<<B_, 256, 0, stream>>>(node, ht, mw, mb, Ahat,
                                 outScorer, outPolicy, outEntropy, t0v, ne0T, A0r);
  k2_gru<<<dim3(B_, 4), 256, 0, stream>>>(Wu, Uu, bu, Wr, Ur, br, Wh, Uh, bh,
                                          ne0T, t0v, prevD, Dw);
  k3_gcn<<<B_, 256, 0, stream>>>(ne0T, Dw, A0r, sw, h1ws, out);
}

// Round 8
// 134.112 us; speedup vs baseline: 2.4789x; 2.2700x over previous
//
#include <hip/hip_runtime.h>
#include <math.h>

// SEM_40200893890649 R8: 7 kernels, max parallelism per phase, min serial work/thread.
//  K1 scorer (32 x 1024) | K2 scores+chunk-top64 (32x8 x 256) | K3 merge (32 x 512)
//  K4 A-gather (32x16 x 256, 1 load/thread) | K5 GRU (32x8, 16-col chunks)
//  K6 GCN layer1 (32x4, 32-col) | K7 GCN layer2 (32x4, 32-col)

namespace {
constexpr int B_ = 32;
constexpr int N_ = 2000;
constexpr int D_ = 128;
constexpr int R_ = 640;

constexpr size_t OFF_SCORER = 0;        // [32][128]
constexpr size_t OFF_INVN   = 4096;     // [32]
constexpr size_t OFF_CANDV  = 4128;     // [32][8][64]
constexpr size_t OFF_CANDI  = 20512;    // int [32][8][64]
constexpr size_t OFF_STATS  = 36896;    // [32][8][3]
constexpr size_t OFF_TKI    = 37664;    // int [32][64]
constexpr size_t OFF_T0     = 39712;    // [32][64]
constexpr size_t OFF_NE0T   = 41760;    // [32][128][64]
constexpr size_t OFF_A0R    = 303904;   // [32][64][64]
constexpr size_t OFF_DW     = 434976;   // [32][128][128]
constexpr size_t OFF_H1     = 959264;   // [32][64][128]
// end 1221408 floats = 4.9 MiB

// =============== K1: scorer, block=1024 ===============
__global__ __launch_bounds__(1024) void k1_scorer(
    const float* __restrict__ ht, const float* __restrict__ mw,
    const float* __restrict__ mb, float* __restrict__ scorer,
    float* __restrict__ invn, float* __restrict__ outScorer) {
  const int b = blockIdx.x, t = threadIdx.x;
  const int d = t & 127, slice = t >> 7;  // 8 slices of 80
  __shared__ float sh[R_];
  __shared__ float part[8][128];
  __shared__ float red[2];
  for (int j = t; j < R_; j += 1024) sh[j] = ht[b * R_ + j];
  __syncthreads();
  const float* wp = mw + (size_t)d * R_ + slice * 80;
  const float* hh = sh + slice * 80;
  float acc = 0.f;
  #pragma unroll
  for (int j = 0; j < 80; j += 4) {
    float4 wv = *reinterpret_cast<const float4*>(wp + j);
    acc += wv.x * hh[j] + wv.y * hh[j + 1] + wv.z * hh[j + 2] + wv.w * hh[j + 3];
  }
  part[slice][d] = acc;
  __syncthreads();
  if (t < 128) {
    float a = mb[t];
    #pragma unroll
    for (int s = 0; s < 8; ++s) a += part[s][t];
    const float sv = tanhf(a);
    scorer[b * D_ + t] = sv;
    outScorer[b * D_ + t] = sv;
    float ss = sv * sv;
    #pragma unroll
    for (int o = 32; o > 0; o >>= 1) ss += __shfl_down(ss, o);
    if ((t & 63) == 0) red[t >> 6] = ss;
  }
  __syncthreads();
  if (t == 0) invn[b] = 1.0f / sqrtf(red[0] + red[1]);
}

// =============== K2: chunk scores + stats + rank-select top-64 (R5 body) ===============
__global__ __launch_bounds__(256) void k2_scores(
    const float* __restrict__ node, const float* __restrict__ scorer,
    const float* __restrict__ invn, float* __restrict__ cand_v,
    int* __restrict__ cand_i, float* __restrict__ stats) {
  const int b = blockIdx.x, c = blockIdx.y, t = threadIdx.x;
  const int lane = t & 63, w = t >> 6;
  __shared__ float sc[D_];
  __shared__ float cv[256];
  __shared__ int ci[256];
  __shared__ float r1[4], r2[4];
  if (t < D_) sc[t] = scorer[b * D_ + t];
  __syncthreads();
  const float inv = invn[b];
  const int n = c * 250 + t;
  const bool valid = t < 250;
  float v = -INFINITY;
  if (valid) {
    const float* row = node + ((size_t)b * N_ + n) * D_;
    float acc = 0.f;
    for (int j = 0; j < D_; j += 4) {
      float4 a = *reinterpret_cast<const float4*>(row + j);
      acc += a.x * sc[j] + a.y * sc[j + 1] + a.z * sc[j + 2] + a.w * sc[j + 3];
    }
    v = acc * inv;
  }
  float m = v;
  #pragma unroll
  for (int o = 32; o > 0; o >>= 1) m = fmaxf(m, __shfl_xor(m, o));
  if (lane == 0) r1[w] = m;
  __syncthreads();
  const float Mc = fmaxf(fmaxf(r1[0], r1[1]), fmaxf(r1[2], r1[3]));
  __syncthreads();
  float se = 0.f, sx = 0.f;
  if (valid) {
    const float x = v - Mc;
    const float e = expf(x);
    se = e;
    sx = x * e;
  }
  #pragma unroll
  for (int o = 32; o > 0; o >>= 1) {
    se += __shfl_xor(se, o);
    sx += __shfl_xor(sx, o);
  }
  if (lane == 0) { r1[w] = se; r2[w] = sx; }
  cv[t] = v;
  ci[t] = valid ? n : 0x7fffffff;
  __syncthreads();
  if (t == 0) {
    float* st = stats + ((size_t)b * 8 + c) * 3;
    st[0] = Mc;
    st[1] = r1[0] + r1[1] + r1[2] + r1[3];
    st[2] = r2[0] + r2[1] + r2[2] + r2[3];
  }
  const float mv = cv[t];
  const int mi = ci[t];
  int rank = 0;
  for (int j = 0; j < 256; ++j) {
    const float jv = cv[j];
    const int ji = ci[j];
    rank += (jv > mv || (jv == mv && ji < mi)) ? 1 : 0;
  }
  if (valid && rank < 64) {
    cand_v[((size_t)b * 8 + c) * 64 + rank] = mv;
    cand_i[((size_t)b * 8 + c) * 64 + rank] = mi;
  }
}

// =============== K3: merge-512 (block 512) + policy/entropy + ne0T ===============
__global__ __launch_bounds__(512) void k3_merge(
    const float* __restrict__ cand_v, const int* __restrict__ cand_i,
    const float* __restrict__ stats, const float* __restrict__ node,
    int* __restrict__ tki, float* __restrict__ t0v,
    float* __restrict__ outPolicy, float* __restrict__ outEntropy,
    float* __restrict__ ne0T) {
  const int b = blockIdx.x, t = threadIdx.x;
  __shared__ float cv[512];
  __shared__ int ci[512];
  __shared__ float sv[64];
  __shared__ int si[64];
  __shared__ float lne[64][132];
  cv[t] = cand_v[(size_t)b * 512 + t];
  ci[t] = cand_i[(size_t)b * 512 + t];
  __syncthreads();
  {
    const float mv = cv[t];
    const int mi = ci[t];
    int rank = 0;
    for (int j = 0; j < 512; ++j) {
      const float jv = cv[j];
      const int ji = ci[j];
      rank += (jv > mv || (jv == mv && ji < mi)) ? 1 : 0;
    }
    if (rank < 64) { sv[rank] = mv; si[rank] = mi; }
  }
  __syncthreads();
  if (t < 64) {
    tki[b * 64 + t] = si[t];
    const float v = sv[t];
    t0v[b * 64 + t] = tanhf(v);
    float s = v;
    #pragma unroll
    for (int o = 32; o > 0; o >>= 1) s += __shfl_xor(s, o);
    if (t == 0) {
      float M = -INFINITY;
      for (int c = 0; c < 8; ++c) M = fmaxf(M, stats[((size_t)b * 8 + c) * 3]);
      float se = 0.f, sx = 0.f;
      for (int c = 0; c < 8; ++c) {
        const float* st = stats + ((size_t)b * 8 + c) * 3;
        const float f = expf(st[0] - M);
        se += f * st[1];
        sx += f * (st[2] + (st[0] - M) * st[1]);
      }
      const float logS = logf(se);
      outPolicy[b] = s * (1.0f / 64.0f) - M - logS;
      outEntropy[b] = logS - sx / se;
    }
  }
  __syncthreads();
  {
    const int k = t >> 3, q = t & 7;  // 64 rows x 8 slices of 16
    const float* src = node + ((size_t)b * N_ + si[k]) * D_ + q * 16;
    #pragma unroll
    for (int j = 0; j < 16; j += 4)
      *reinterpret_cast<float4*>(&lne[k][q * 16 + j]) =
          *reinterpret_cast<const float4*>(src + j);
  }
  __syncthreads();
  {
    const int f = t >> 2, kh = (t & 3) * 16;  // 128 rows x 4 slices of 16
    float* dst = ne0T + ((size_t)b * D_ + f) * 64 + kh;
    #pragma unroll
    for (int j = 0; j < 16; j += 4) {
      float4 vv;
      vv.x = lne[kh + j][f];
      vv.y = lne[kh + j + 1][f];
      vv.z = lne[kh + j + 2][f];
      vv.w = lne[kh + j + 3][f];
      *reinterpret_cast<float4*>(dst + j) = vv;
    }
  }
}

// =============== K4: A-gather, 1 scattered load per thread ===============
__global__ __launch_bounds__(256) void k4_agather(
    const float* __restrict__ Ahat, const int* __restrict__ tki,
    float* __restrict__ A0r) {
  const int b = blockIdx.x, y = blockIdx.y, t = threadIdx.x;
  __shared__ int idx[64];
  if (t < 64) idx[t] = tki[b * 64 + t];
  __syncthreads();
  const int row = y * 4 + (t >> 6);
  const int col = t & 63;
  A0r[(size_t)b * 4096 + row * 64 + col] =
      Ahat[(size_t)b * N_ * N_ + (size_t)idx[row] * N_ + idx[col]];
}

// =============== K5: fused GRU, 16-col chunks (grid 32x8) ===============
__global__ __launch_bounds__(256) void k5_gru(
    const float* __restrict__ Wu, const float* __restrict__ Uu, const float* __restrict__ bu,
    const float* __restrict__ Wr, const float* __restrict__ Ur, const float* __restrict__ br,
    const float* __restrict__ Wh, const float* __restrict__ Uh, const float* __restrict__ bh,
    const float* __restrict__ ne0T, const float* __restrict__ t0v,
    const float* __restrict__ P, float* __restrict__ Dw) {
  const int b = blockIdx.x, c = blockIdx.y;  // c 0..7
  const int t = threadIdx.x, tx = t & 15, ty = t >> 4;
  __shared__ float Wt[16][132], Ut[16][132];
  __shared__ float Xt[16][17], Yt[16][17];
  __shared__ float gs[2][128][17];
  __shared__ float t0s[16];
  const int col = c * 16 + tx;
  const int kq = col & 63;
  if (t < 16) t0s[t] = t0v[b * 64 + (c & 3) * 16 + t];
  const float* neT = ne0T + (size_t)b * D_ * 64;
  const float* Pb = P + (size_t)b * D_ * D_;
  for (int z = 0; z < 2; ++z) {
    const float* W = z ? Wr : Wu;
    const float* U = z ? Ur : Uu;
    const float* bb = z ? br : bu;
    float acc[8] = {};
    for (int f0 = 0; f0 < D_; f0 += 16) {
      __syncthreads();
      #pragma unroll
      for (int rr = 0; rr < 8; rr++) {
        const int i = rr * 16 + ty;
        Wt[tx][i] = W[i * D_ + f0 + tx];
        Ut[tx][i] = U[i * D_ + f0 + tx];
      }
      Xt[ty][tx] = neT[(f0 + ty) * 64 + kq] * t0s[tx];
      Yt[ty][tx] = Pb[(f0 + ty) * D_ + col];
      __syncthreads();
      #pragma unroll
      for (int ff = 0; ff < 16; ff++) {
        const float xv = Xt[ff][tx];
        const float yv = Yt[ff][tx];
        const float4 wa = *reinterpret_cast<const float4*>(&Wt[ff][ty * 8]);
        const float4 wb = *reinterpret_cast<const float4*>(&Wt[ff][ty * 8 + 4]);
        const float4 ua = *reinterpret_cast<const float4*>(&Ut[ff][ty * 8]);
        const float4 ub = *reinterpret_cast<const float4*>(&Ut[ff][ty * 8 + 4]);
        acc[0] += wa.x * xv + ua.x * yv;
        acc[1] += wa.y * xv + ua.y * yv;
        acc[2] += wa.z * xv + ua.z * yv;
        acc[3] += wa.w * xv + ua.w * yv;
        acc[4] += wb.x * xv + ub.x * yv;
        acc[5] += wb.y * xv + ub.y * yv;
        acc[6] += wb.z * xv + ub.z * yv;
        acc[7] += wb.w * xv + ub.w * yv;
      }
    }
    #pragma unroll
    for (int r = 0; r < 8; r++) {
      const int i = ty * 8 + r;
      const float zz = acc[r] + bb[i * D_ + col];
      gs[z][i][tx] = 1.f / (1.f + expf(-zz));
    }
  }
  float acc[8] = {};
  for (int f0 = 0; f0 < D_; f0 += 16) {
    __syncthreads();
    #pragma unroll
    for (int rr = 0; rr < 8; rr++) {
      const int i = rr * 16 + ty;
      Wt[tx][i] = Wh[i * D_ + f0 + tx];
      Ut[tx][i] = Uh[i * D_ + f0 + tx];
    }
    Xt[ty][tx] = neT[(f0 + ty) * 64 + kq] * t0s[tx];
    Yt[ty][tx] = gs[1][f0 + ty][tx] * Pb[(f0 + ty) * D_ + col];
    __syncthreads();
    #pragma unroll
    for (int ff = 0; ff < 16; ff++) {
      const float xv = Xt[ff][tx];
      const float yv = Yt[ff][tx];
      const float4 wa = *reinterpret_cast<const float4*>(&Wt[ff][ty * 8]);
      const float4 wb = *reinterpret_cast<const float4*>(&Wt[ff][ty * 8 + 4]);
      const float4 ua = *reinterpret_cast<const float4*>(&Ut[ff][ty * 8]);
      const float4 ub = *reinterpret_cast<const float4*>(&Ut[ff][ty * 8 + 4]);
      acc[0] += wa.x * xv + ua.x * yv;
      acc[1] += wa.y * xv + ua.y * yv;
      acc[2] += wa.z * xv + ua.z * yv;
      acc[3] += wa.w * xv + ua.w * yv;
      acc[4] += wb.x * xv + ub.x * yv;
      acc[5] += wb.y * xv + ub.y * yv;
      acc[6] += wb.z * xv + ub.z * yv;
      acc[7] += wb.w * xv + ub.w * yv;
    }
  }
  #pragma unroll
  for (int r = 0; r < 8; r++) {
    const int i = ty * 8 + r;
    const size_t off = ((size_t)b * D_ + i) * D_ + col;
    const float hh = tanhf(acc[r] + bh[i * D_ + col]);
    const float uu = gs[0][i][tx];
    const float pp = Pb[i * D_ + col];
    Dw[off] = (1.f - uu) * pp + uu * hh;
  }
}

// =============== shared GCN helper: stage + normalize A in LDS ===============
// =============== K6: GCN layer1, 32-col chunks (grid 32x4) ===============
__global__ __launch_bounds__(256) void k6_gcn1(
    const float* __restrict__ ne0T, const float* __restrict__ Dw,
    const float* __restrict__ A0r, float* __restrict__ h1ws) {
  const int b = blockIdx.x, c = blockIdx.y;
  const int t = threadIdx.x, tx = t & 15, ty = t >> 4;
  __shared__ float As[64][68];
  __shared__ float di[64];
  __shared__ float At[16][68];
  __shared__ float Bt[16][36];
  __shared__ float Ts[64][36];
  const float* Ab = A0r + (size_t)b * 4096;
  const float* neT = ne0T + (size_t)b * D_ * 64;
  const float* Db = Dw + (size_t)b * D_ * D_;
  #pragma unroll
  for (int ph = 0; ph < 4; ++ph) {
    const int i = ph * 16 + ty;
    *reinterpret_cast<float4*>(&As[i][tx * 4]) =
        *reinterpret_cast<const float4*>(Ab + i * 64 + tx * 4);
  }
  __syncthreads();
  if (t < 64) {
    float s = 0.f;
    #pragma unroll
    for (int i = 0; i < 64; ++i) s += As[i][t];
    di[t] = 1.0f / sqrtf(2.0f * s);
  }
  __syncthreads();
  #pragma unroll
  for (int ph = 0; ph < 4; ++ph) {
    const int i = ph * 16 + ty;
    const float sI = 2.0f * di[i];
    float4 v = *reinterpret_cast<float4*>(&As[i][tx * 4]);
    v.x *= sI * di[tx * 4];
    v.y *= sI * di[tx * 4 + 1];
    v.z *= sI * di[tx * 4 + 2];
    v.w *= sI * di[tx * 4 + 3];
    *reinterpret_cast<float4*>(&As[i][tx * 4]) = v;
  }
  // phase 1: t1 chunk (64 x 32) = ne0 @ Dw[:, c*32..]
  const int colg = t & 7, rowg = t >> 3;  // 8x4 cols, 32x2 rows
  float acc[2][4] = {};
  for (int f0 = 0; f0 < D_; f0 += 16) {
    __syncthreads();
    {
      const int ff = t >> 4, i4 = (t & 15) * 4;
      *reinterpret_cast<float4*>(&At[ff][i4]) =
          *reinterpret_cast<const float4*>(neT + (f0 + ff) * 64 + i4);
      const int j2 = (t & 15) * 2;
      *reinterpret_cast<float2*>(&Bt[ff][j2]) =
          *reinterpret_cast<const float2*>(Db + (f0 + ff) * D_ + c * 32 + j2);
    }
    __syncthreads();
    #pragma unroll
    for (int ff = 0; ff < 16; ff++) {
      const float a0 = At[ff][rowg * 2];
      const float a1 = At[ff][rowg * 2 + 1];
      const float4 b4 = *reinterpret_cast<const float4*>(&Bt[ff][colg * 4]);
      acc[0][0] += a0 * b4.x; acc[0][1] += a0 * b4.y;
      acc[0][2] += a0 * b4.z; acc[0][3] += a0 * b4.w;
      acc[1][0] += a1 * b4.x; acc[1][1] += a1 * b4.y;
      acc[1][2] += a1 * b4.z; acc[1][3] += a1 * b4.w;
    }
  }
  __syncthreads();
  #pragma unroll
  for (int r = 0; r < 2; r++) {
    float4 o = {acc[r][0], acc[r][1], acc[r][2], acc[r][3]};
    *reinterpret_cast<float4*>(&Ts[rowg * 2 + r][colg * 4]) = o;
  }
  __syncthreads();
  // phase 2: h1 chunk = relu(An @ t1chunk), K=64
  float acc2[2][4] = {};
  for (int ff = 0; ff < 64; ++ff) {
    const float a0 = As[rowg * 2][ff];
    const float a1 = As[rowg * 2 + 1][ff];
    const float4 b4 = *reinterpret_cast<const float4*>(&Ts[ff][colg * 4]);
    acc2[0][0] += a0 * b4.x; acc2[0][1] += a0 * b4.y;
    acc2[0][2] += a0 * b4.z; acc2[0][3] += a0 * b4.w;
    acc2[1][0] += a1 * b4.x; acc2[1][1] += a1 * b4.y;
    acc2[1][2] += a1 * b4.z; acc2[1][3] += a1 * b4.w;
  }
  #pragma unroll
  for (int r = 0; r < 2; r++) {
    float4 o = {fmaxf(acc2[r][0], 0.f), fmaxf(acc2[r][1], 0.f),
                fmaxf(acc2[r][2], 0.f), fmaxf(acc2[r][3], 0.f)};
    *reinterpret_cast<float4*>(h1ws + ((size_t)b * 64 + rowg * 2 + r) * D_ +
                               c * 32 + colg * 4) = o;
  }
}

// =============== K7: GCN layer2 + epilogue, 32-col chunks (grid 32x4) ===============
__global__ __launch_bounds__(256) void k7_gcn2(
    const float* __restrict__ h1ws, const float* __restrict__ sw,
    const float* __restrict__ A0r, float* __restrict__ out) {
  const int b = blockIdx.x, c = blockIdx.y;
  const int t = threadIdx.x, tx = t & 15, ty = t >> 4;
  __shared__ float As[64][68];
  __shared__ float di[64];
  __shared__ float At[16][68];
  __shared__ float Bt[16][36];
  __shared__ float Ts[64][36];
  const float* Ab = A0r + (size_t)b * 4096;
  const float* h1b = h1ws + (size_t)b * 64 * D_;
  #pragma unroll
  for (int ph = 0; ph < 4; ++ph) {
    const int i = ph * 16 + ty;
    *reinterpret_cast<float4*>(&As[i][tx * 4]) =
        *reinterpret_cast<const float4*>(Ab + i * 64 + tx * 4);
  }
  __syncthreads();
  if (t < 64) {
    float s = 0.f;
    #pragma unroll
    for (int i = 0; i < 64; ++i) s += As[i][t];
    di[t] = 1.0f / sqrtf(2.0f * s);
  }
  __syncthreads();
  #pragma unroll
  for (int ph = 0; ph < 4; ++ph) {
    const int i = ph * 16 + ty;
    const float sI = 2.0f * di[i];
    float4 v = *reinterpret_cast<float4*>(&As[i][tx * 4]);
    v.x *= sI * di[tx * 4];
    v.y *= sI * di[tx * 4 + 1];
    v.z *= sI * di[tx * 4 + 2];
    v.w *= sI * di[tx * 4 + 3];
    *reinterpret_cast<float4*>(&As[i][tx * 4]) = v;
  }
  // phase 1: t2 chunk = h1 @ sw[:, c*32..]
  const int colg = t & 7, rowg = t >> 3;
  float acc[2][4] = {};
  for (int f0 = 0; f0 < D_; f0 += 16) {
    __syncthreads();
    {
      const int ff = t >> 4, i4 = (t & 15) * 4;
      #pragma unroll
      for (int s = 0; s < 4; ++s)
        At[ff][i4 + s] = h1b[(i4 + s) * D_ + f0 + ff];
      const int j2 = (t & 15) * 2;
      *reinterpret_cast<float2*>(&Bt[ff][j2]) =
          *reinterpret_cast<const float2*>(sw + (f0 + ff) * D_ + c * 32 + j2);
    }
    __syncthreads();
    #pragma unroll
    for (int ff = 0; ff < 16; ff++) {
      const float a0 = At[ff][rowg * 2];
      const float a1 = At[ff][rowg * 2 + 1];
      const float4 b4 = *reinterpret_cast<const float4*>(&Bt[ff][colg * 4]);
      acc[0][0] += a0 * b4.x; acc[0][1] += a0 * b4.y;
      acc[0][2] += a0 * b4.z; acc[0][3] += a0 * b4.w;
      acc[1][0] += a1 * b4.x; acc[1][1] += a1 * b4.y;
      acc[1][2] += a1 * b4.z; acc[1][3] += a1 * b4.w;
    }
  }
  __syncthreads();
  #pragma unroll
  for (int r = 0; r < 2; r++) {
    float4 o = {acc[r][0], acc[r][1], acc[r][2], acc[r][3]};
    *reinterpret_cast<float4*>(&Ts[rowg * 2 + r][colg * 4]) = o;
  }
  __syncthreads();
  // phase 2: h2 = relu(An @ t2chunk); out = 0.5*(h1+h2), rows duplicated
  float acc2[2][4] = {};
  for (int ff = 0; ff < 64; ++ff) {
    const float a0 = As[rowg * 2][ff];
    const float a1 = As[rowg * 2 + 1][ff];
    const float4 b4 = *reinterpret_cast<const float4*>(&Ts[ff][colg * 4]);
    acc2[0][0] += a0 * b4.x; acc2[0][1] += a0 * b4.y;
    acc2[0][2] += a0 * b4.z; acc2[0][3] += a0 * b4.w;
    acc2[1][0] += a1 * b4.x; acc2[1][1] += a1 * b4.y;
    acc2[1][2] += a1 * b4.z; acc2[1][3] += a1 * b4.w;
  }
  #pragma unroll
  for (int r = 0; r < 2; r++) {
    const int i = rowg * 2 + r;
    const int k = c * 32 + colg * 4;
    const float4 h1v = *reinterpret_cast<const float4*>(h1b + i * D_ + k);
    float4 o;
    o.x = 0.5f * (h1v.x + fmaxf(acc2[r][0], 0.f));
    o.y = 0.5f * (h1v.y + fmaxf(acc2[r][1], 0.f));
    o.z = 0.5f * (h1v.z + fmaxf(acc2[r][2], 0.f));
    o.w = 0.5f * (h1v.w + fmaxf(acc2[r][3], 0.f));
    *reinterpret_cast<float4*>(out + ((size_t)b * D_ + i) * D_ + k) = o;
    *reinterpret_cast<float4*>(out + ((size_t)b * D_ + i + 64) * D_ + k) = o;
  }
}

}  // namespace

extern "C" void kernel_launch(void* const* d_in, const int* in_sizes, int n_in,
                              void* d_out, int out_size, void* d_ws, size_t ws_size,
                              hipStream_t stream) {
  (void)in_sizes; (void)n_in; (void)out_size; (void)ws_size;
  const float* Ahat = (const float*)d_in[0];
  const float* node = (const float*)d_in[1];
  const float* ht   = (const float*)d_in[2];
  const float* prevD= (const float*)d_in[3];
  const float* mw   = (const float*)d_in[4];
  const float* mb   = (const float*)d_in[5];
  const float* Wu   = (const float*)d_in[6];
  const float* Uu   = (const float*)d_in[7];
  const float* bu   = (const float*)d_in[8];
  const float* Wr   = (const float*)d_in[9];
  const float* Ur   = (const float*)d_in[10];
  const float* br   = (const float*)d_in[11];
  const float* Wh   = (const float*)d_in[12];
  const float* Uh   = (const float*)d_in[13];
  const float* bh   = (const float*)d_in[14];
  const float* sw   = (const float*)d_in[15];

  float* out = (float*)d_out;
  float* outPolicy  = out + (size_t)B_ * D_ * D_;
  float* outScorer  = outPolicy + B_;
  float* outEntropy = outScorer + (size_t)B_ * D_;

  float* ws = (float*)d_ws;
  float* scorer = ws + OFF_SCORER;
  float* invn   = ws + OFF_INVN;
  float* cand_v = ws + OFF_CANDV;
  int*   cand_i = (int*)(ws + OFF_CANDI);
  float* stats  = ws + OFF_STATS;
  int*   tki    = (int*)(ws + OFF_TKI);
  float* t0v    = ws + OFF_T0;
  float* ne0T   = ws + OFF_NE0T;
  float* A0r    = ws + OFF_A0R;
  float* Dw     = ws + OFF_DW;
  float* h1ws   = ws + OFF_H1;

  k1_scorer<<<B_, 1024, 0, stream>>>(ht, mw, mb, scorer, invn, outScorer);
  k2_scores<<<dim3(B_, 8), 256, 0, stream>>>(node, scorer, invn, cand_v, cand_i, stats);
  k3_merge<<<B_, 512, 0, stream>>>(cand_v, cand_i, stats, node, tki, t0v,
                                   outPolicy, outEntropy, ne0T);
  k4_agather<<<dim3(B_, 16), 256, 0, stream>>>(Ahat, tki, A0r);
  k5_gru<<<dim3(B_, 8), 256, 0, stream>>>(Wu, Uu, bu, Wr, Ur, br, Wh, Uh, bh,
                                          ne0T, t0v, prevD, Dw);
  k6_gcn1<<<dim3(B_, 4), 256, 0, stream>>>(ne0T, Dw, A0r, h1ws);
  k7_gcn2<<<dim3(B_, 4), 256, 0, stream>>>(h1ws, sw, A0r, out);
}

// Round 9
// 123.276 us; speedup vs baseline: 2.6968x; 1.0879x over previous
//
#include <hip/hip_runtime.h>
#include <math.h>

// SEM_40200893890649 R9: split serial work again.
//  K1 scorer (32 x 1024) | K2 scores split-dot/split-rank (32x8 x 512)
//  K3 merge split-rank (32 x 1024) | K4 A-gather 1 load/thread (32x16)
//  K5 GRU 8-col chunks (32x16) | K6 GCN1 16-col (32x8) | K7 GCN2 16-col (32x8)

namespace {
constexpr int B_ = 32;
constexpr int N_ = 2000;
constexpr int D_ = 128;
constexpr int R_ = 640;

constexpr size_t OFF_SCORER = 0;        // [32][128]
constexpr size_t OFF_INVN   = 4096;     // [32]
constexpr size_t OFF_CANDV  = 4128;     // [32][8][64]
constexpr size_t OFF_CANDI  = 20512;    // int [32][8][64]
constexpr size_t OFF_STATS  = 36896;    // [32][8][3]
constexpr size_t OFF_TKI    = 37664;    // int [32][64]
constexpr size_t OFF_T0     = 39712;    // [32][64]
constexpr size_t OFF_NE0T   = 41760;    // [32][128][64]
constexpr size_t OFF_A0R    = 303904;   // [32][64][64]
constexpr size_t OFF_DW     = 434976;   // [32][128][128]
constexpr size_t OFF_H1     = 959264;   // [32][64][128]
// end 1221408 floats = 4.9 MiB

// =============== K1: scorer, block=1024 (R8 body) ===============
__global__ __launch_bounds__(1024) void k1_scorer(
    const float* __restrict__ ht, const float* __restrict__ mw,
    const float* __restrict__ mb, float* __restrict__ scorer,
    float* __restrict__ invn, float* __restrict__ outScorer) {
  const int b = blockIdx.x, t = threadIdx.x;
  const int d = t & 127, slice = t >> 7;
  __shared__ float sh[R_];
  __shared__ float part[8][128];
  __shared__ float red[2];
  for (int j = t; j < R_; j += 1024) sh[j] = ht[b * R_ + j];
  __syncthreads();
  const float* wp = mw + (size_t)d * R_ + slice * 80;
  const float* hh = sh + slice * 80;
  float acc = 0.f;
  #pragma unroll
  for (int j = 0; j < 80; j += 4) {
    float4 wv = *reinterpret_cast<const float4*>(wp + j);
    acc += wv.x * hh[j] + wv.y * hh[j + 1] + wv.z * hh[j + 2] + wv.w * hh[j + 3];
  }
  part[slice][d] = acc;
  __syncthreads();
  if (t < 128) {
    float a = mb[t];
    #pragma unroll
    for (int s = 0; s < 8; ++s) a += part[s][t];
    const float sv = tanhf(a);
    scorer[b * D_ + t] = sv;
    outScorer[b * D_ + t] = sv;
    float ss = sv * sv;
    #pragma unroll
    for (int o = 32; o > 0; o >>= 1) ss += __shfl_down(ss, o);
    if ((t & 63) == 0) red[t >> 6] = ss;
  }
  __syncthreads();
  if (t == 0) invn[b] = 1.0f / sqrtf(red[0] + red[1]);
}

// =============== K2: chunk scores, split dot + split rank (block 512) ===============
__global__ __launch_bounds__(512) void k2_scores(
    const float* __restrict__ node, const float* __restrict__ scorer,
    const float* __restrict__ invn, float* __restrict__ cand_v,
    int* __restrict__ cand_i, float* __restrict__ stats) {
  const int b = blockIdx.x, c = blockIdx.y, t = threadIdx.x;
  const int cand = t & 255, s = t >> 8;
  const int lane = t & 63, w = t >> 6;
  __shared__ float sc[D_];
  __shared__ float pd[256][2];
  __shared__ float cv[256];
  __shared__ int ci[256];
  __shared__ int pr[256][2];
  __shared__ float r1[8], r2[8];
  if (t < D_) sc[t] = scorer[b * D_ + t];
  __syncthreads();
  const float inv = invn[b];
  const int n = c * 250 + cand;
  const bool valid = cand < 250;
  // half-dot over D-slice s
  {
    float acc = 0.f;
    if (valid) {
      const float* row = node + ((size_t)b * N_ + n) * D_ + s * 64;
      const float* scp = sc + s * 64;
      #pragma unroll
      for (int j = 0; j < 64; j += 4) {
        float4 a = *reinterpret_cast<const float4*>(row + j);
        acc += a.x * scp[j] + a.y * scp[j + 1] + a.z * scp[j + 2] + a.w * scp[j + 3];
      }
    }
    pd[cand][s] = acc;
  }
  __syncthreads();
  float v = -INFINITY;
  if (s == 0 && valid) v = (pd[cand][0] + pd[cand][1]) * inv;
  // block max (slice-1 contributes -INF)
  float m = v;
  #pragma unroll
  for (int o = 32; o > 0; o >>= 1) m = fmaxf(m, __shfl_xor(m, o));
  if (lane == 0) r1[w] = m;
  __syncthreads();
  float Mc = r1[0];
  #pragma unroll
  for (int q = 1; q < 8; ++q) Mc = fmaxf(Mc, r1[q]);
  __syncthreads();
  // softmax partials (slice-1 contributes 0)
  float se = 0.f, sx = 0.f;
  if (s == 0 && valid) {
    const float x = v - Mc;
    const float e = expf(x);
    se = e;
    sx = x * e;
  }
  #pragma unroll
  for (int o = 32; o > 0; o >>= 1) {
    se += __shfl_xor(se, o);
    sx += __shfl_xor(sx, o);
  }
  if (lane == 0) { r1[w] = se; r2[w] = sx; }
  if (s == 0) {
    cv[cand] = v;
    ci[cand] = valid ? n : 0x7fffffff;
  }
  __syncthreads();
  if (t == 0) {
    float Se = 0.f, Sx = 0.f;
    #pragma unroll
    for (int q = 0; q < 8; ++q) { Se += r1[q]; Sx += r2[q]; }
    float* st = stats + ((size_t)b * 8 + c) * 3;
    st[0] = Mc;
    st[1] = Se;
    st[2] = Sx;
  }
  // split rank: slice s covers j in [s*128, s*128+128)
  {
    const float mv = cv[cand];
    const int mi = ci[cand];
    int rank = 0;
    const int j0 = s * 128;
    for (int j = j0; j < j0 + 128; ++j) {
      const float jv = cv[j];
      const int ji = ci[j];
      rank += (jv > mv || (jv == mv && ji < mi)) ? 1 : 0;
    }
    pr[cand][s] = rank;
  }
  __syncthreads();
  if (s == 0 && valid) {
    const int rk = pr[cand][0] + pr[cand][1];
    if (rk < 64) {
      cand_v[((size_t)b * 8 + c) * 64 + rk] = cv[cand];
      cand_i[((size_t)b * 8 + c) * 64 + rk] = ci[cand];
    }
  }
}

// =============== K3: merge-512 split-rank (block 1024) + policy/entropy + ne0T ===============
__global__ __launch_bounds__(1024) void k3_merge(
    const float* __restrict__ cand_v, const int* __restrict__ cand_i,
    const float* __restrict__ stats, const float* __restrict__ node,
    int* __restrict__ tki, float* __restrict__ t0v,
    float* __restrict__ outPolicy, float* __restrict__ outEntropy,
    float* __restrict__ ne0T) {
  const int b = blockIdx.x, t = threadIdx.x;
  const int cand = t & 511, s = t >> 9;
  __shared__ float cv[512];
  __shared__ int ci[512];
  __shared__ int pr[512][2];
  __shared__ float sv[64];
  __shared__ int si[64];
  __shared__ float lne[64][132];
  if (t < 512) {
    cv[t] = cand_v[(size_t)b * 512 + t];
    ci[t] = cand_i[(size_t)b * 512 + t];
  }
  __syncthreads();
  {
    const float mv = cv[cand];
    const int mi = ci[cand];
    int rank = 0;
    const int j0 = s * 256;
    for (int j = j0; j < j0 + 256; ++j) {
      const float jv = cv[j];
      const int ji = ci[j];
      rank += (jv > mv || (jv == mv && ji < mi)) ? 1 : 0;
    }
    pr[cand][s] = rank;
  }
  __syncthreads();
  if (s == 0) {
    const int rk = pr[cand][0] + pr[cand][1];
    if (rk < 64) { sv[rk] = cv[cand]; si[rk] = ci[cand]; }
  }
  __syncthreads();
  if (t < 64) {
    tki[b * 64 + t] = si[t];
    const float v = sv[t];
    t0v[b * 64 + t] = tanhf(v);
    float sum = v;
    #pragma unroll
    for (int o = 32; o > 0; o >>= 1) sum += __shfl_xor(sum, o);
    if (t == 0) {
      float M = -INFINITY;
      for (int c = 0; c < 8; ++c) M = fmaxf(M, stats[((size_t)b * 8 + c) * 3]);
      float se = 0.f, sx = 0.f;
      for (int c = 0; c < 8; ++c) {
        const float* st = stats + ((size_t)b * 8 + c) * 3;
        const float f = expf(st[0] - M);
        se += f * st[1];
        sx += f * (st[2] + (st[0] - M) * st[1]);
      }
      const float logS = logf(se);
      outPolicy[b] = sum * (1.0f / 64.0f) - M - logS;
      outEntropy[b] = logS - sx / se;
    }
  }
  __syncthreads();
  // lne gather: 64 rows x 128, 1024 threads -> 8 floats each
  {
    const int k = t >> 4, q = t & 15;
    const float* src = node + ((size_t)b * N_ + si[k]) * D_ + q * 8;
    *reinterpret_cast<float4*>(&lne[k][q * 8]) =
        *reinterpret_cast<const float4*>(src);
    *reinterpret_cast<float4*>(&lne[k][q * 8 + 4]) =
        *reinterpret_cast<const float4*>(src + 4);
  }
  __syncthreads();
  // ne0T: 128 rows x 64, 8 floats each
  {
    const int f = t >> 3, kh = (t & 7) * 8;
    float* dst = ne0T + ((size_t)b * D_ + f) * 64 + kh;
    float4 a, bq;
    a.x = lne[kh][f];     a.y = lne[kh + 1][f];
    a.z = lne[kh + 2][f]; a.w = lne[kh + 3][f];
    bq.x = lne[kh + 4][f]; bq.y = lne[kh + 5][f];
    bq.z = lne[kh + 6][f]; bq.w = lne[kh + 7][f];
    *reinterpret_cast<float4*>(dst) = a;
    *reinterpret_cast<float4*>(dst + 4) = bq;
  }
}

// =============== K4: A-gather, 1 scattered load per thread (R8 body) ===============
__global__ __launch_bounds__(256) void k4_agather(
    const float* __restrict__ Ahat, const int* __restrict__ tki,
    float* __restrict__ A0r) {
  const int b = blockIdx.x, y = blockIdx.y, t = threadIdx.x;
  __shared__ int idx[64];
  if (t < 64) idx[t] = tki[b * 64 + t];
  __syncthreads();
  const int row = y * 4 + (t >> 6);
  const int col = t & 63;
  A0r[(size_t)b * 4096 + row * 64 + col] =
      Ahat[(size_t)b * N_ * N_ + (size_t)idx[row] * N_ + idx[col]];
}

// =============== K5: fused GRU, 8-col chunks (grid 32x16), 4 rows/thread ===============
__global__ __launch_bounds__(256) void k5_gru(
    const float* __restrict__ Wu, const float* __restrict__ Uu, const float* __restrict__ bu,
    const float* __restrict__ Wr, const float* __restrict__ Ur, const float* __restrict__ br,
    const float* __restrict__ Wh, const float* __restrict__ Uh, const float* __restrict__ bh,
    const float* __restrict__ ne0T, const float* __restrict__ t0v,
    const float* __restrict__ P, float* __restrict__ Dw) {
  const int b = blockIdx.x, c = blockIdx.y;  // c 0..15
  const int t = threadIdx.x;
  const int tx = t & 7, ty = t >> 3;        // col-in-chunk, row-group (4 rows)
  const int sx_ = t & 15, sy_ = t >> 4;     // staging coords
  __shared__ float Wt[16][132], Ut[16][132];
  __shared__ float Xt[16][9], Yt[16][9];
  __shared__ float gs[2][128][9];
  __shared__ float t0s[8];
  const int col = c * 8 + tx;
  const int kq = (c & 7) * 8 + tx;  // col & 63
  if (t < 8) t0s[t] = t0v[b * 64 + (c & 7) * 8 + t];
  const float* neT = ne0T + (size_t)b * D_ * 64;
  const float* Pb = P + (size_t)b * D_ * D_;
  for (int z = 0; z < 2; ++z) {
    const float* W = z ? Wr : Wu;
    const float* U = z ? Ur : Uu;
    const float* bb = z ? br : bu;
    float acc[4] = {};
    for (int f0 = 0; f0 < D_; f0 += 16) {
      __syncthreads();
      #pragma unroll
      for (int rr = 0; rr < 8; rr++) {
        const int i = rr * 16 + sy_;
        Wt[sx_][i] = W[i * D_ + f0 + sx_];
        Ut[sx_][i] = U[i * D_ + f0 + sx_];
      }
      if (t < 128) {
        const int ff = t >> 3, kk = t & 7;
        Xt[ff][kk] = neT[(f0 + ff) * 64 + (c & 7) * 8 + kk] * t0s[kk];
        Yt[ff][kk] = Pb[(f0 + ff) * D_ + c * 8 + kk];
      }
      __syncthreads();
      #pragma unroll
      for (int ff = 0; ff < 16; ff++) {
        const float xv = Xt[ff][tx];
        const float yv = Yt[ff][tx];
        const float4 wa = *reinterpret_cast<const float4*>(&Wt[ff][ty * 4]);
        const float4 ua = *reinterpret_cast<const float4*>(&Ut[ff][ty * 4]);
        acc[0] += wa.x * xv + ua.x * yv;
        acc[1] += wa.y * xv + ua.y * yv;
        acc[2] += wa.z * xv + ua.z * yv;
        acc[3] += wa.w * xv + ua.w * yv;
      }
    }
    #pragma unroll
    for (int r = 0; r < 4; r++) {
      const int i = ty * 4 + r;
      const float zz = acc[r] + bb[i * D_ + col];
      gs[z][i][tx] = 1.f / (1.f + expf(-zz));
    }
  }
  float acc[4] = {};
  for (int f0 = 0; f0 < D_; f0 += 16) {
    __syncthreads();
    #pragma unroll
    for (int rr = 0; rr < 8; rr++) {
      const int i = rr * 16 + sy_;
      Wt[sx_][i] = Wh[i * D_ + f0 + sx_];
      Ut[sx_][i] = Uh[i * D_ + f0 + sx_];
    }
    if (t < 128) {
      const int ff = t >> 3, kk = t & 7;
      Xt[ff][kk] = neT[(f0 + ff) * 64 + (c & 7) * 8 + kk] * t0s[kk];
      Yt[ff][kk] = gs[1][f0 + ff][kk] * Pb[(f0 + ff) * D_ + c * 8 + kk];
    }
    __syncthreads();
    #pragma unroll
    for (int ff = 0; ff < 16; ff++) {
      const float xv = Xt[ff][tx];
      const float yv = Yt[ff][tx];
      const float4 wa = *reinterpret_cast<const float4*>(&Wt[ff][ty * 4]);
      const float4 ua = *reinterpret_cast<const float4*>(&Ut[ff][ty * 4]);
      acc[0] += wa.x * xv + ua.x * yv;
      acc[1] += wa.y * xv + ua.y * yv;
      acc[2] += wa.z * xv + ua.z * yv;
      acc[3] += wa.w * xv + ua.w * yv;
    }
  }
  #pragma unroll
  for (int r = 0; r < 4; r++) {
    const int i = ty * 4 + r;
    const size_t off = ((size_t)b * D_ + i) * D_ + col;
    const float hh = tanhf(acc[r] + bh[i * D_ + col]);
    const float uu = gs[0][i][tx];
    const float pp = Pb[i * D_ + col];
    Dw[off] = (1.f - uu) * pp + uu * hh;
  }
}

// =============== K6: GCN layer1, 16-col chunks (grid 32x8), 1 row x 4 cols/thread ===============
__global__ __launch_bounds__(256) void k6_gcn1(
    const float* __restrict__ ne0T, const float* __restrict__ Dw,
    const float* __restrict__ A0r, float* __restrict__ h1ws) {
  const int b = blockIdx.x, c = blockIdx.y;  // c 0..7
  const int t = threadIdx.x;
  const int tx = t & 15, ty = t >> 4;        // staging coords
  const int colg = t & 3, rowg = t >> 2;     // compute coords: 1 row x 4 cols
  __shared__ float As[64][68];
  __shared__ float di[64];
  __shared__ float At[16][68];
  __shared__ float Bt[16][20];
  __shared__ float Ts[64][20];
  const float* Ab = A0r + (size_t)b * 4096;
  const float* neT = ne0T + (size_t)b * D_ * 64;
  const float* Db = Dw + (size_t)b * D_ * D_;
  #pragma unroll
  for (int ph = 0; ph < 4; ++ph) {
    const int i = ph * 16 + ty;
    *reinterpret_cast<float4*>(&As[i][tx * 4]) =
        *reinterpret_cast<const float4*>(Ab + i * 64 + tx * 4);
  }
  __syncthreads();
  if (t < 64) {
    float s = 0.f;
    #pragma unroll
    for (int i = 0; i < 64; ++i) s += As[i][t];
    di[t] = 1.0f / sqrtf(2.0f * s);
  }
  __syncthreads();
  #pragma unroll
  for (int ph = 0; ph < 4; ++ph) {
    const int i = ph * 16 + ty;
    const float sI = 2.0f * di[i];
    float4 v = *reinterpret_cast<float4*>(&As[i][tx * 4]);
    v.x *= sI * di[tx * 4];
    v.y *= sI * di[tx * 4 + 1];
    v.z *= sI * di[tx * 4 + 2];
    v.w *= sI * di[tx * 4 + 3];
    *reinterpret_cast<float4*>(&As[i][tx * 4]) = v;
  }
  // phase 1: t1 chunk (64 x 16) = ne0 @ Dw[:, c*16..]
  float acc[4] = {};
  for (int f0 = 0; f0 < D_; f0 += 16) {
    __syncthreads();
    {
      *reinterpret_cast<float4*>(&At[ty][tx * 4]) =
          *reinterpret_cast<const float4*>(neT + (f0 + ty) * 64 + tx * 4);
      Bt[ty][tx] = Db[(f0 + ty) * D_ + c * 16 + tx];
    }
    __syncthreads();
    #pragma unroll
    for (int ff = 0; ff < 16; ff++) {
      const float a = At[ff][rowg];
      const float4 b4 = *reinterpret_cast<const float4*>(&Bt[ff][colg * 4]);
      acc[0] += a * b4.x;
      acc[1] += a * b4.y;
      acc[2] += a * b4.z;
      acc[3] += a * b4.w;
    }
  }
  __syncthreads();
  {
    float4 o = {acc[0], acc[1], acc[2], acc[3]};
    *reinterpret_cast<float4*>(&Ts[rowg][colg * 4]) = o;
  }
  __syncthreads();
  // phase 2: h1 chunk = relu(An @ t1chunk), K=64
  float acc2[4] = {};
  for (int ff = 0; ff < 64; ++ff) {
    const float a = As[rowg][ff];
    const float4 b4 = *reinterpret_cast<const float4*>(&Ts[ff][colg * 4]);
    acc2[0] += a * b4.x;
    acc2[1] += a * b4.y;
    acc2[2] += a * b4.z;
    acc2[3] += a * b4.w;
  }
  {
    float4 o = {fmaxf(acc2[0], 0.f), fmaxf(acc2[1], 0.f),
                fmaxf(acc2[2], 0.f), fmaxf(acc2[3], 0.f)};
    *reinterpret_cast<float4*>(h1ws + ((size_t)b * 64 + rowg) * D_ +
                               c * 16 + colg * 4) = o;
  }
}

// =============== K7: GCN layer2 + epilogue, 16-col chunks (grid 32x8) ===============
__global__ __launch_bounds__(256) void k7_gcn2(
    const float* __restrict__ h1ws, const float* __restrict__ sw,
    const float* __restrict__ A0r, float* __restrict__ out) {
  const int b = blockIdx.x, c = blockIdx.y;
  const int t = threadIdx.x;
  const int tx = t & 15, ty = t >> 4;
  const int colg = t & 3, rowg = t >> 2;
  __shared__ float As[64][68];
  __shared__ float di[64];
  __shared__ float At[16][68];
  __shared__ float Bt[16][20];
  __shared__ float Ts[64][20];
  const float* Ab = A0r + (size_t)b * 4096;
  const float* h1b = h1ws + (size_t)b * 64 * D_;
  #pragma unroll
  for (int ph = 0; ph < 4; ++ph) {
    const int i = ph * 16 + ty;
    *reinterpret_cast<float4*>(&As[i][tx * 4]) =
        *reinterpret_cast<const float4*>(Ab + i * 64 + tx * 4);
  }
  __syncthreads();
  if (t < 64) {
    float s = 0.f;
    #pragma unroll
    for (int i = 0; i < 64; ++i) s += As[i][t];
    di[t] = 1.0f / sqrtf(2.0f * s);
  }
  __syncthreads();
  #pragma unroll
  for (int ph = 0; ph < 4; ++ph) {
    const int i = ph * 16 + ty;
    const float sI = 2.0f * di[i];
    float4 v = *reinterpret_cast<float4*>(&As[i][tx * 4]);
    v.x *= sI * di[tx * 4];
    v.y *= sI * di[tx * 4 + 1];
    v.z *= sI * di[tx * 4 + 2];
    v.w *= sI * di[tx * 4 + 3];
    *reinterpret_cast<float4*>(&As[i][tx * 4]) = v;
  }
  // phase 1: t2 chunk = h1 @ sw[:, c*16..]
  float acc[4] = {};
  for (int f0 = 0; f0 < D_; f0 += 16) {
    __syncthreads();
    {
      const int i4 = tx * 4;
      #pragma unroll
      for (int s = 0; s < 4; ++s)
        At[ty][i4 + s] = h1b[(i4 + s) * D_ + f0 + ty];
      Bt[ty][tx] = sw[(f0 + ty) * D_ + c * 16 + tx];
    }
    __syncthreads();
    #pragma unroll
    for (int ff = 0; ff < 16; ff++) {
      const float a = At[ff][rowg];
      const float4 b4 = *reinterpret_cast<const float4*>(&Bt[ff][colg * 4]);
      acc[0] += a * b4.x;
      acc[1] += a * b4.y;
      acc[2] += a * b4.z;
      acc[3] += a * b4.w;
    }
  }
  __syncthreads();
  {
    float4 o = {acc[0], acc[1], acc[2], acc[3]};
    *reinterpret_cast<float4*>(&Ts[rowg][colg * 4]) = o;
  }
  __syncthreads();
  // phase 2: h2 = relu(An @ t2chunk); out = 0.5*(h1+h2), rows duplicated
  float acc2[4] = {};
  for (int ff = 0; ff < 64; ++ff) {
    const float a = As[rowg][ff];
    const float4 b4 = *reinterpret_cast<const float4*>(&Ts[ff][colg * 4]);
    acc2[0] += a * b4.x;
    acc2[1] += a * b4.y;
    acc2[2] += a * b4.z;
    acc2[3] += a * b4.w;
  }
  {
    const int k = c * 16 + colg * 4;
    const float4 h1v = *reinterpret_cast<const float4*>(h1b + rowg * D_ + k);
    float4 o;
    o.x = 0.5f * (h1v.x + fmaxf(acc2[0], 0.f));
    o.y = 0.5f * (h1v.y + fmaxf(acc2[1], 0.f));
    o.z = 0.5f * (h1v.z + fmaxf(acc2[2], 0.f));
    o.w = 0.5f * (h1v.w + fmaxf(acc2[3], 0.f));
    *reinterpret_cast<float4*>(out + ((size_t)b * D_ + rowg) * D_ + k) = o;
    *reinterpret_cast<float4*>(out + ((size_t)b * D_ + rowg + 64) * D_ + k) = o;
  }
}

}  // namespace

extern "C" void kernel_launch(void* const* d_in, const int* in_sizes, int n_in,
                              void* d_out, int out_size, void* d_ws, size_t ws_size,
                              hipStream_t stream) {
  (void)in_sizes; (void)n_in; (void)out_size; (void)ws_size;
  const float* Ahat = (const float*)d_in[0];
  const float* node = (const float*)d_in[1];
  const float* ht   = (const float*)d_in[2];
  const float* prevD= (const float*)d_in[3];
  const float* mw   = (const float*)d_in[4];
  const float* mb   = (const float*)d_in[5];
  const float* Wu   = (const float*)d_in[6];
  const float* Uu   = (const float*)d_in[7];
  const float* bu   = (const float*)d_in[8];
  const float* Wr   = (const float*)d_in[9];
  const float* Ur   = (const float*)d_in[10];
  const float* br   = (const float*)d_in[11];
  const float* Wh   = (const float*)d_in[12];
  const float* Uh   = (const float*)d_in[13];
  const float* bh   = (const float*)d_in[14];
  const float* sw   = (const float*)d_in[15];

  float* out = (float*)d_out;
  float* outPolicy  = out + (size_t)B_ * D_ * D_;
  float* outScorer  = outPolicy + B_;
  float* outEntropy = outScorer + (size_t)B_ * D_;

  float* ws = (float*)d_ws;
  float* scorer = ws + OFF_SCORER;
  float* invn   = ws + OFF_INVN;
  float* cand_v = ws + OFF_CANDV;
  int*   cand_i = (int*)(ws + OFF_CANDI);
  float* stats  = ws + OFF_STATS;
  int*   tki    = (int*)(ws + OFF_TKI);
  float* t0v    = ws + OFF_T0;
  float* ne0T   = ws + OFF_NE0T;
  float* A0r    = ws + OFF_A0R;
  float* Dw     = ws + OFF_DW;
  float* h1ws   = ws + OFF_H1;

  k1_scorer<<<B_, 1024, 0, stream>>>(ht, mw, mb, scorer, invn, outScorer);
  k2_scores<<<dim3(B_, 8), 512, 0, stream>>>(node, scorer, invn, cand_v, cand_i, stats);
  k3_merge<<<B_, 1024, 0, stream>>>(cand_v, cand_i, stats, node, tki, t0v,
                                    outPolicy, outEntropy, ne0T);
  k4_agather<<<dim3(B_, 16), 256, 0, stream>>>(Ahat, tki, A0r);
  k5_gru<<<dim3(B_, 16), 256, 0, stream>>>(Wu, Uu, bu, Wr, Ur, br, Wh, Uh, bh,
                                           ne0T, t0v, prevD, Dw);
  k6_gcn1<<<dim3(B_, 8), 256, 0, stream>>>(ne0T, Dw, A0r, h1ws);
  k7_gcn2<<<dim3(B_, 8), 256, 0, stream>>>(h1ws, sw, A0r, out);
}